// Round 4
// baseline (1845.069 us; speedup 1.0000x reference)
//
#include <hip/hip_runtime.h>
#include <hip/hip_fp16.h>
#include <hip/hip_cooperative_groups.h>
#include <math.h>

namespace cg = cooperative_groups;

#define D 25
#define STATS_BLOCKS 512
#define NBKT 512        // buckets of 512 nodes
#define BSH 9
#define BMSK 511
#define BIN_EDGES 8192  // edges per bin block
#define SORT_CAP 10240  // LDS sort capacity per bucket (avg ~8.2k)
#define NSLOT 64        // replicated stat partial slots
#define GBLK 1024       // cooperative gather grid (256 CU x 4 blocks, guaranteed resident)
#define NPB 8           // node-group batches per block: 1024*8*32 = 262144 >= N cap
#define EPS 1e-5f

typedef unsigned int u32;
typedef unsigned long long u64;

// ---------------- binA: per-(block,bucket) histogram + stPart zeroing ----------------
__global__ __launch_bounds__(256) void binA(const int* __restrict__ dst,
                                            int* __restrict__ hist2D,
                                            float* __restrict__ stPart, int E) {
    if (blockIdx.x < 25) stPart[blockIdx.x * 256 + threadIdx.x] = 0.0f;
    __shared__ int h[NBKT];
    h[threadIdx.x] = 0;
    h[threadIdx.x + 256] = 0;
    __syncthreads();
    int base = blockIdx.x * BIN_EDGES;
#pragma unroll
    for (int j = 0; j < 32; ++j) {
        int idx = base + j * 256 + threadIdx.x;
        if (idx < E) atomicAdd(&h[dst[idx] >> BSH], 1);
    }
    __syncthreads();
    hist2D[blockIdx.x * NBKT + threadIdx.x] = h[threadIdx.x];
    hist2D[blockIdx.x * NBKT + threadIdx.x + 256] = h[threadIdx.x + 256];
}

// ------- colscan: per bucket, exclusive scan over blocks (in place) + total -------
__global__ __launch_bounds__(512) void colscan(int* __restrict__ hist2D,
                                               int* __restrict__ bCount, int nbBin) {
    __shared__ int s[512];
    int b = blockIdx.x;
    int j = threadIdx.x;
    int v = (j < nbBin) ? hist2D[j * NBKT + b] : 0;
    s[j] = v;
    __syncthreads();
    for (int off = 1; off < 512; off <<= 1) {
        int x = (j >= off) ? s[j - off] : 0;
        __syncthreads();
        s[j] += x;
        __syncthreads();
    }
    if (j < nbBin) hist2D[j * NBKT + b] = s[j] - v;   // exclusive prefix
    if (j == 0) bCount[b] = s[511];
}

// ------- binB (512 thr): inline scan of bCount for bases; write keys grouped by bucket -------
__global__ __launch_bounds__(512) void binB(const int* __restrict__ src,
                                            const int* __restrict__ dst,
                                            const int* __restrict__ hist2D,
                                            const int* __restrict__ bCount,
                                            int* __restrict__ binned, int E) {
    __shared__ int rank[NBKT], basew[NBKT], sc[NBKT];
    int t = threadIdx.x;
    int cnt = bCount[t];
    sc[t] = cnt;
    rank[t] = 0;
    __syncthreads();
    for (int off = 1; off < NBKT; off <<= 1) {
        int x = (t >= off) ? sc[t - off] : 0;
        __syncthreads();
        sc[t] += x;
        __syncthreads();
    }
    basew[t] = (sc[t] - cnt) + hist2D[blockIdx.x * NBKT + t];
    __syncthreads();
    int base = blockIdx.x * BIN_EDGES;
#pragma unroll
    for (int j = 0; j < 16; ++j) {
        int idx = base + j * 512 + t;
        if (idx < E) {
            int d = dst[idx];
            int b = d >> BSH;
            int r = atomicAdd(&rank[b], 1);
            binned[basew[b] + r] = (src[idx] << BSH) | (d & BMSK);
        }
    }
}

// ------- bucket_fill (512 thr): sort bucket b (512 nodes) in LDS; each row partitioned
//         [src < Nhalf | src >= Nhalf]; mid[node] = global start of the high part -------
__global__ __launch_bounds__(512) void bucket_fill(
        const int* __restrict__ binned, const int* __restrict__ bCount,
        int* __restrict__ degi, int* __restrict__ cursor, int* __restrict__ mid,
        int* __restrict__ csr, int N, int Nhalf) {
    int b = blockIdx.x;
    int nodeBase = b << BSH;
    if (nodeBase >= N) return;
    __shared__ int h[NBKT];      // low histogram / low write-cursor
    __shared__ int hHi[NBKT];    // high histogram / high write-cursor
    __shared__ int s2[512];
    __shared__ int sorted[SORT_CAP];
    int t = threadIdx.x;
    // parallel reduce of bCount[0..b-1] into base
    s2[t] = (t < b) ? bCount[t] : 0;
    __syncthreads();
    for (int off = 256; off > 0; off >>= 1) {
        if (t < off) s2[t] += s2[t + off];
        __syncthreads();
    }
    int s = s2[0];
    __syncthreads();
    h[t] = 0;
    hHi[t] = 0;
    __syncthreads();
    int cnt = bCount[b];
    int e = s + cnt;
    // per-(node, src-half) degree histogram
    for (int k = s + t; k < e; k += 512) {
        int key = binned[k];
        if ((key >> BSH) >= Nhalf) atomicAdd(&hHi[key & BMSK], 1);
        else                       atomicAdd(&h[key & BMSK], 1);
    }
    __syncthreads();
    int lo = h[t], hc = hHi[t];
    int dg = lo + hc;
    int node = nodeBase + t;
    if (node < N) degi[node] = dg;
    s2[t] = dg;
    __syncthreads();
    for (int off = 1; off < 512; off <<= 1) {
        int x = (t >= off) ? s2[t - off] : 0;
        __syncthreads();
        s2[t] += x;
        __syncthreads();
    }
    int rowstart = s2[t] - dg;         // local row start
    if (node < N) {
        cursor[node] = s + s2[t];      // global row end
        mid[node]    = s + rowstart + lo;  // global start of high-src part
    }
    h[t]   = rowstart;                 // low write-cursor (local)
    hHi[t] = rowstart + lo;            // high write-cursor (local)
    __syncthreads();
    if (cnt <= SORT_CAP) {
        // scatter into LDS, then coalesced writeout
        for (int k = s + t; k < e; k += 512) {
            int key = binned[k];
            int bb = key & BMSK;
            int p = ((key >> BSH) >= Nhalf) ? atomicAdd(&hHi[bb], 1)
                                            : atomicAdd(&h[bb], 1);
            sorted[p] = key >> BSH;
        }
        __syncthreads();
        for (int j = t; j < cnt; j += 512)
            csr[s + j] = sorted[j];
    } else {
        // overflow fallback: direct global scatter
        for (int k = s + t; k < e; k += 512) {
            int key = binned[k];
            int bb = key & BMSK;
            int p = ((key >> BSH) >= Nhalf) ? atomicAdd(&hHi[bb], 1)
                                            : atomicAdd(&h[bb], 1);
            csr[s + p] = key >> BSH;
        }
    }
}

// ================= int8-quantized row format =================
// row = 32 B: dwords 0..6 hold 25 int8 (bytes 25..27 zero), dword 7 = fp32 scale.
// value[d] = (int8)byte[d] * scale.  scale = rowmax/127, round-to-nearest.

__device__ __forceinline__ void quant_store_q8(u32* __restrict__ P8, int i,
                                               const float* v) {
    float mx = 0.0f;
#pragma unroll
    for (int d = 0; d < D; ++d) mx = fmaxf(mx, fabsf(v[d]));
    float scale = mx * (1.0f / 127.0f);
    float inv = (mx > 0.0f) ? (127.0f / mx) : 0.0f;
    u32 w[8];
#pragma unroll
    for (int dw = 0; dw < 7; ++dw) {
        u32 p = 0;
#pragma unroll
        for (int j = 0; j < 4; ++j) {
            int d = dw * 4 + j;
            int q = (d < D) ? __float2int_rn(v[d] * inv) : 0;
            p |= ((u32)q & 255u) << (8 * j);
        }
        w[dw] = p;
    }
    w[7] = __float_as_uint(scale);
    uint4* o = (uint4*)(P8 + ((size_t)i << 3));
    o[0] = make_uint4(w[0], w[1], w[2], w[3]);
    o[1] = make_uint4(w[4], w[5], w[6], w[7]);
}

__device__ __forceinline__ void acc_q8(u32 w, float c,
                                       float& a0, float& a1, float& a2, float& a3) {
    a0 = fmaf(c, (float)((int)(w << 24) >> 24), a0);
    a1 = fmaf(c, (float)((int)(w << 16) >> 24), a1);
    a2 = fmaf(c, (float)((int)(w <<  8) >> 24), a2);
    a3 = fmaf(c, (float)((int)w >> 24), a3);
}

// walk edge range [k, end): 8 edges in flight, 8-lane group, lane f = dword of row
__device__ __forceinline__ void walk_q8(const int* __restrict__ csr,
                                        const u32* __restrict__ P8, int k, int end,
                                        int f, float& a0, float& a1, float& a2, float& a3) {
    for (; k + 8 <= end; k += 8) {
        int e0 = __builtin_nontemporal_load(csr + k);
        int e1 = __builtin_nontemporal_load(csr + k + 1);
        int e2 = __builtin_nontemporal_load(csr + k + 2);
        int e3 = __builtin_nontemporal_load(csr + k + 3);
        int e4 = __builtin_nontemporal_load(csr + k + 4);
        int e5 = __builtin_nontemporal_load(csr + k + 5);
        int e6 = __builtin_nontemporal_load(csr + k + 6);
        int e7 = __builtin_nontemporal_load(csr + k + 7);
        u32 w0 = P8[((size_t)e0 << 3) + f];
        u32 w1 = P8[((size_t)e1 << 3) + f];
        u32 w2 = P8[((size_t)e2 << 3) + f];
        u32 w3 = P8[((size_t)e3 << 3) + f];
        u32 w4 = P8[((size_t)e4 << 3) + f];
        u32 w5 = P8[((size_t)e5 << 3) + f];
        u32 w6 = P8[((size_t)e6 << 3) + f];
        u32 w7 = P8[((size_t)e7 << 3) + f];
        float c0 = __shfl(__uint_as_float(w0), 7, 8);
        float c1 = __shfl(__uint_as_float(w1), 7, 8);
        float c2 = __shfl(__uint_as_float(w2), 7, 8);
        float c3 = __shfl(__uint_as_float(w3), 7, 8);
        float c4 = __shfl(__uint_as_float(w4), 7, 8);
        float c5 = __shfl(__uint_as_float(w5), 7, 8);
        float c6 = __shfl(__uint_as_float(w6), 7, 8);
        float c7 = __shfl(__uint_as_float(w7), 7, 8);
        acc_q8(w0, c0, a0, a1, a2, a3);
        acc_q8(w1, c1, a0, a1, a2, a3);
        acc_q8(w2, c2, a0, a1, a2, a3);
        acc_q8(w3, c3, a0, a1, a2, a3);
        acc_q8(w4, c4, a0, a1, a2, a3);
        acc_q8(w5, c5, a0, a1, a2, a3);
        acc_q8(w6, c6, a0, a1, a2, a3);
        acc_q8(w7, c7, a0, a1, a2, a3);
    }
    for (; k < end; ++k) {
        int e = __builtin_nontemporal_load(csr + k);
        u32 w = P8[((size_t)e << 3) + f];
        float c = __shfl(__uint_as_float(w), 7, 8);
        acc_q8(w, c, a0, a1, a2, a3);
    }
}

// ------------- layer1: P8 = q8(dinv * (emb[x] @ W1)) -------------
__global__ __launch_bounds__(256) void embed_gemm1_q8(
        const int* __restrict__ x, const float* __restrict__ emb,
        const float* __restrict__ W1, const int* __restrict__ degi,
        u32* __restrict__ P8, int N) {
    __shared__ float sW[D * D];
    for (int j = threadIdx.x; j < D * D; j += blockDim.x) sW[j] = W1[j];
    __syncthreads();
    int i = blockIdx.x * blockDim.x + threadIdx.x;
    if (i >= N) return;
    const float* er = emb + (size_t)x[i] * D;
    float t[D];
#pragma unroll
    for (int k = 0; k < D; ++k) t[k] = er[k];
    float dinv = rsqrtf((float)degi[i] + 1.0f);
    float v[D];
#pragma unroll
    for (int d = 0; d < D; ++d) {
        float acc = 0.0f;
#pragma unroll
        for (int k = 0; k < D; ++k) acc = fmaf(t[k], sW[k * D + d], acc);
        v[d] = dinv * acc;
    }
    quant_store_q8(P8, i, v);
}

// ------- cooperative phased gather: phase A = src<Nhalf (3.2 MB rows, L2-resident),
//         grid barrier, phase B = src>=Nhalf + bias/dinv + Qh write + BN stats -------
__global__ __launch_bounds__(256, 4) void gather_coop(
        const int* __restrict__ csr, const int* __restrict__ cursor,
        const int* __restrict__ mid, const int* __restrict__ degi,
        const u32* __restrict__ P8, const float* __restrict__ bias,
        __half* __restrict__ Qh, float* __restrict__ stPart, int N, int Nhalf) {
    __shared__ float red[4][8][8];
    int t = threadIdx.x;
    int f = t & 7;
    int grp = t >> 3;
    float acc[NPB][4];
    cg::grid_group grid = cg::this_grid();
    // ---- phase A ----
#pragma unroll
    for (int b = 0; b < NPB; ++b) {
        acc[b][0] = 0.0f; acc[b][1] = 0.0f; acc[b][2] = 0.0f; acc[b][3] = 0.0f;
        int node = (blockIdx.x + b * gridDim.x) * 32 + grp;
        if (node < N) {
            int end = cursor[node];
            int m   = mid[node];
            int k   = end - degi[node];
            if (node < Nhalf) {   // self loop lives in the low half
                u32 w = P8[((size_t)node << 3) + f];
                float c = __shfl(__uint_as_float(w), 7, 8);
                acc_q8(w, c, acc[b][0], acc[b][1], acc[b][2], acc[b][3]);
            }
            walk_q8(csr, P8, k, m, f, acc[b][0], acc[b][1], acc[b][2], acc[b][3]);
        }
    }
    grid.sync();
    // ---- phase B ----
    float r0 = 0, r1 = 0, r2 = 0, r3 = 0, r4 = 0, r5 = 0, r6 = 0, r7 = 0;
#pragma unroll
    for (int b = 0; b < NPB; ++b) {
        int node = (blockIdx.x + b * gridDim.x) * 32 + grp;
        float q0 = 0.f, q1 = 0.f, q2 = 0.f, q3 = 0.f;
        if (node < N) {
            int end = cursor[node];
            int m   = mid[node];
            if (node >= Nhalf) {
                u32 w = P8[((size_t)node << 3) + f];
                float c = __shfl(__uint_as_float(w), 7, 8);
                acc_q8(w, c, acc[b][0], acc[b][1], acc[b][2], acc[b][3]);
            }
            walk_q8(csr, P8, m, end, f, acc[b][0], acc[b][1], acc[b][2], acc[b][3]);
            float dinv = rsqrtf((float)degi[node] + 1.0f);
            int j0 = f << 2;
            if (f < 7) {
                q0 = fmaf(dinv, acc[b][0], bias[j0]);
                if (j0 + 1 < D) q1 = fmaf(dinv, acc[b][1], bias[j0 + 1]);
                if (j0 + 2 < D) q2 = fmaf(dinv, acc[b][2], bias[j0 + 2]);
                if (j0 + 3 < D) q3 = fmaf(dinv, acc[b][3], bias[j0 + 3]);
            }
            __half2 h01 = __floats2half2_rn(q0, q1);
            __half2 h23 = __floats2half2_rn(q2, q3);
            union { __half2 h[2]; u64 u; } cv;
            cv.h[0] = h01; cv.h[1] = h23;
            __builtin_nontemporal_store(cv.u, (u64*)Qh + ((size_t)node << 3) + f);
        }
        r0 += q0; r1 += q1; r2 += q2; r3 += q3;
        r4 += q0 * q0; r5 += q1 * q1; r6 += q2 * q2; r7 += q3 * q3;
    }
    // ---- fused BN stats ----
    float r[8] = {r0, r1, r2, r3, r4, r5, r6, r7};
#pragma unroll
    for (int v = 0; v < 8; ++v) {
        r[v] += __shfl_down(r[v], 32, 64);
        r[v] += __shfl_down(r[v], 16, 64);
        r[v] += __shfl_down(r[v], 8, 64);
    }
    int wv = t >> 6;
    if ((t & 63) < 8) {
#pragma unroll
        for (int v = 0; v < 8; ++v) red[wv][f][v] = r[v];
    }
    __syncthreads();
    if (t < 64) {
        int ff = t >> 3, v = t & 7;
        float tot = red[0][ff][v] + red[1][ff][v] + red[2][ff][v] + red[3][ff][v];
        int a = (ff << 2) + (v & 3);
        if (a < D)
            atomicAdd(&stPart[(blockIdx.x & (NSLOT - 1)) * 50 + (v >> 2) * D + a], tot);
    }
}

// ------- non-coop fallback gather (Round-3 verified kernel) -------
__global__ __launch_bounds__(256) void gather_stats_q8(
        const int* __restrict__ csr, const int* __restrict__ cursor,
        const int* __restrict__ degi, const u32* __restrict__ P8,
        const float* __restrict__ bias, __half* __restrict__ Qh,
        float* __restrict__ stPart, int N) {
    __shared__ float red[4][8][8];
    int t = threadIdx.x;
    int node = blockIdx.x * 32 + (t >> 3);
    int f = t & 7;
    float a0 = 0.f, a1 = 0.f, a2 = 0.f, a3 = 0.f;
    float q0 = 0.f, q1 = 0.f, q2 = 0.f, q3 = 0.f;
    if (node < N) {
        int end = cursor[node];
        int dg  = degi[node];
        int k = end - dg;
        u32 wsf = P8[((size_t)node << 3) + f];
        float csf = __shfl(__uint_as_float(wsf), 7, 8);
        acc_q8(wsf, csf, a0, a1, a2, a3);
        walk_q8(csr, P8, k, end, f, a0, a1, a2, a3);
        float dinv = rsqrtf((float)dg + 1.0f);
        int j0 = f << 2;
        if (f < 7) {
            q0 = fmaf(dinv, a0, bias[j0]);
            if (j0 + 1 < D) q1 = fmaf(dinv, a1, bias[j0 + 1]);
            if (j0 + 2 < D) q2 = fmaf(dinv, a2, bias[j0 + 2]);
            if (j0 + 3 < D) q3 = fmaf(dinv, a3, bias[j0 + 3]);
        }
        __half2 h01 = __floats2half2_rn(q0, q1);
        __half2 h23 = __floats2half2_rn(q2, q3);
        union { __half2 h[2]; u64 u; } cv;
        cv.h[0] = h01; cv.h[1] = h23;
        __builtin_nontemporal_store(cv.u, (u64*)Qh + ((size_t)node << 3) + f);
    }
    float r[8] = {q0, q1, q2, q3, q0 * q0, q1 * q1, q2 * q2, q3 * q3};
#pragma unroll
    for (int v = 0; v < 8; ++v) {
        r[v] += __shfl_down(r[v], 32, 64);
        r[v] += __shfl_down(r[v], 16, 64);
        r[v] += __shfl_down(r[v], 8, 64);
    }
    int wv = t >> 6;
    if ((t & 63) < 8) {
#pragma unroll
        for (int v = 0; v < 8; ++v) red[wv][f][v] = r[v];
    }
    __syncthreads();
    if (t < 64) {
        int ff = t >> 3, v = t & 7;
        float tot = red[0][ff][v] + red[1][ff][v] + red[2][ff][v] + red[3][ff][v];
        int a = (ff << 2) + (v & 3);
        if (a < D)
            atomicAdd(&stPart[(blockIdx.x & (NSLOT - 1)) * 50 + (v >> 2) * D + a], tot);
    }
}

// ------- layer2: reduce stPart -> mu/rstd; t = relu(bn(Qh)); P8 = q8(dinv*(t@W2)) -------
__global__ __launch_bounds__(256) void bn_gemm_q8(
        const __half* __restrict__ Qh, const float* __restrict__ stPart, float invN,
        const float* __restrict__ g, const float* __restrict__ be,
        const float* __restrict__ W, const int* __restrict__ degi,
        u32* __restrict__ P8, int N) {
    __shared__ float sW[D * D];
    __shared__ float sScale[D], sShift[D];
    __shared__ float sSum[2 * D];
    for (int j = threadIdx.x; j < D * D; j += blockDim.x) sW[j] = W[j];
    if (threadIdx.x < 2 * D) {
        float a = 0.0f;
        for (int k = 0; k < NSLOT; ++k) a += stPart[k * 50 + threadIdx.x];
        sSum[threadIdx.x] = a;
    }
    __syncthreads();
    if (threadIdx.x < D) {
        float m = sSum[threadIdx.x] * invN;
        float v = fmaxf(sSum[D + threadIdx.x] * invN - m * m, 0.0f);
        float sc = rsqrtf(v + EPS) * g[threadIdx.x];
        sScale[threadIdx.x] = sc;
        sShift[threadIdx.x] = be[threadIdx.x] - m * sc;
    }
    __syncthreads();
    int i = blockIdx.x * blockDim.x + threadIdx.x;
    if (i >= N) return;
    const __half2* qrow = (const __half2*)Qh + ((size_t)i << 4);
    float t[D];
#pragma unroll
    for (int ff = 0; ff < 13; ++ff) {
        float2 v = __half22float2(qrow[ff]);
        int j0 = ff << 1;
        t[j0] = fmaxf(0.0f, fmaf(v.x, sScale[j0], sShift[j0]));
        if (ff < 12) t[j0 + 1] = fmaxf(0.0f, fmaf(v.y, sScale[j0 + 1], sShift[j0 + 1]));
    }
    float dinv = rsqrtf((float)degi[i] + 1.0f);
    float vout[D];
#pragma unroll
    for (int d = 0; d < D; ++d) {
        float acc = 0.0f;
#pragma unroll
        for (int k = 0; k < D; ++k) acc = fmaf(t[k], sW[k * D + d], acc);
        vout[d] = dinv * acc;
    }
    quant_store_q8(P8, i, vout);
}

// ------- head: reduce stPart -> mu/rstd; t = relu(bn(Qh)); MLP; sigmoid -------
__global__ __launch_bounds__(256) void final_kernel_p(
        const __half* __restrict__ Qh, const float* __restrict__ stPart, float invN,
        const float* __restrict__ g, const float* __restrict__ be,
        const float* __restrict__ Wm1, const float* __restrict__ bm1,
        const float* __restrict__ Wm2, const float* __restrict__ bm2,
        float* __restrict__ out, int N) {
    __shared__ float sW1[D * 12];
    __shared__ float sb1[12], sW2[12];
    __shared__ float sScale[D], sShift[D];
    __shared__ float sSum[2 * D];
    __shared__ float sb2;
    for (int j = threadIdx.x; j < D * 12; j += blockDim.x) sW1[j] = Wm1[j];
    if (threadIdx.x < 12) {
        sb1[threadIdx.x] = bm1[threadIdx.x];
        sW2[threadIdx.x] = Wm2[threadIdx.x];
    }
    if (threadIdx.x < 2 * D) {
        float a = 0.0f;
        for (int k = 0; k < NSLOT; ++k) a += stPart[k * 50 + threadIdx.x];
        sSum[threadIdx.x] = a;
    }
    if (threadIdx.x == 0) sb2 = bm2[0];
    __syncthreads();
    if (threadIdx.x < D) {
        float m = sSum[threadIdx.x] * invN;
        float v = fmaxf(sSum[D + threadIdx.x] * invN - m * m, 0.0f);
        float sc = rsqrtf(v + EPS) * g[threadIdx.x];
        sScale[threadIdx.x] = sc;
        sShift[threadIdx.x] = be[threadIdx.x] - m * sc;
    }
    __syncthreads();
    int i = blockIdx.x * blockDim.x + threadIdx.x;
    if (i >= N) return;
    const __half2* qrow = (const __half2*)Qh + ((size_t)i << 4);
    float t[D];
#pragma unroll
    for (int ff = 0; ff < 13; ++ff) {
        float2 v = __half22float2(qrow[ff]);
        int j0 = ff << 1;
        t[j0] = fmaxf(0.0f, fmaf(v.x, sScale[j0], sShift[j0]));
        if (ff < 12) t[j0 + 1] = fmaxf(0.0f, fmaf(v.y, sScale[j0 + 1], sShift[j0 + 1]));
    }
    float z = sb2;
#pragma unroll
    for (int j = 0; j < 12; ++j) {
        float m = sb1[j];
#pragma unroll
        for (int k = 0; k < D; ++k) m = fmaf(t[k], sW1[k * 12 + j], m);
        m = fmaxf(0.0f, m);
        z = fmaf(m, sW2[j], z);
    }
    out[i] = 1.0f / (1.0f + expf(-z));
}

// ================= fallback kernels (atomic-scatter path, fp32) =================
__global__ void hist_kernel(const int* __restrict__ dst, int* __restrict__ degi, int E) {
    int e = blockIdx.x * blockDim.x + threadIdx.x;
    if (e < E) atomicAdd(&degi[dst[e]], 1);
}

__global__ __launch_bounds__(256) void embed_gemm1(
        const int* __restrict__ x, const float* __restrict__ emb,
        const float* __restrict__ W1, const int* __restrict__ degi,
        float* __restrict__ P, float* __restrict__ Qdup, int N) {
    __shared__ float sW[D * D];
    for (int j = threadIdx.x; j < D * D; j += blockDim.x) sW[j] = W1[j];
    __syncthreads();
    int i = blockIdx.x * blockDim.x + threadIdx.x;
    if (i >= N) return;
    const float* er = emb + (size_t)x[i] * D;
    float t[D];
#pragma unroll
    for (int k = 0; k < D; ++k) t[k] = er[k];
    float dinv = rsqrtf((float)degi[i] + 1.0f);
#pragma unroll
    for (int d = 0; d < D; ++d) {
        float acc = 0.0f;
#pragma unroll
        for (int k = 0; k < D; ++k) acc = fmaf(t[k], sW[k * D + d], acc);
        float v = dinv * acc;
        P[i * D + d] = v;
        if (Qdup) Qdup[i * D + d] = v;
    }
}

__global__ void scatter_kernel(const int* __restrict__ src, const int* __restrict__ dst,
                               const float* __restrict__ A, float* __restrict__ B, int E) {
    int idx = blockIdx.x * blockDim.x + threadIdx.x;
    int e = idx >> 5;
    int lane = idx & 31;
    if (e >= E || lane >= D) return;
    atomicAdd(&B[dst[e] * D + lane], A[src[e] * D + lane]);
}

__global__ __launch_bounds__(256) void transform_kernel(
        float* __restrict__ Q, const int* __restrict__ degi,
        const float* __restrict__ bias, int N) {
    int i = blockIdx.x * blockDim.x + threadIdx.x;
    if (i >= N) return;
    float dinv = rsqrtf((float)degi[i] + 1.0f);
#pragma unroll
    for (int d = 0; d < D; ++d)
        Q[i * D + d] = fmaf(dinv, Q[i * D + d], bias[d]);
}

__global__ __launch_bounds__(256) void stats_kernel(
        const float* __restrict__ Q, float* __restrict__ st, int N) {
    float ls[D], lq[D];
#pragma unroll
    for (int d = 0; d < D; ++d) { ls[d] = 0.0f; lq[d] = 0.0f; }
    for (int i = blockIdx.x * blockDim.x + threadIdx.x; i < N;
         i += gridDim.x * blockDim.x) {
#pragma unroll
        for (int d = 0; d < D; ++d) {
            float v = Q[i * D + d];
            ls[d] += v;
            lq[d] += v * v;
        }
    }
#pragma unroll
    for (int d = 0; d < D; ++d) {
        for (int off = 32; off > 0; off >>= 1) {
            ls[d] += __shfl_down(ls[d], off, 64);
            lq[d] += __shfl_down(lq[d], off, 64);
        }
    }
    __shared__ float red[4][2 * D];
    int wave = threadIdx.x >> 6;
    int lane = threadIdx.x & 63;
    if (lane == 0) {
#pragma unroll
        for (int d = 0; d < D; ++d) {
            red[wave][d] = ls[d];
            red[wave][D + d] = lq[d];
        }
    }
    __syncthreads();
    if (threadIdx.x < 2 * D) {
        float t = red[0][threadIdx.x] + red[1][threadIdx.x] +
                  red[2][threadIdx.x] + red[3][threadIdx.x];
        atomicAdd(&st[threadIdx.x], t);
    }
}

__global__ __launch_bounds__(256) void bn_gemm(
        const float* __restrict__ Qin, const float* __restrict__ st, float invN,
        const float* __restrict__ g, const float* __restrict__ be,
        const float* __restrict__ W, const int* __restrict__ degi,
        float* __restrict__ P, float* __restrict__ Qdup, int N) {
    __shared__ float sW[D * D];
    __shared__ float sScale[D], sShift[D];
    for (int j = threadIdx.x; j < D * D; j += blockDim.x) sW[j] = W[j];
    if (threadIdx.x < D) {
        float m = st[threadIdx.x] * invN;
        float v = fmaxf(st[D + threadIdx.x] * invN - m * m, 0.0f);
        float sc = rsqrtf(v + EPS) * g[threadIdx.x];
        sScale[threadIdx.x] = sc;
        sShift[threadIdx.x] = be[threadIdx.x] - m * sc;
    }
    __syncthreads();
    int i = blockIdx.x * blockDim.x + threadIdx.x;
    if (i >= N) return;
    float t[D];
#pragma unroll
    for (int d = 0; d < D; ++d)
        t[d] = fmaxf(0.0f, fmaf(Qin[i * D + d], sScale[d], sShift[d]));
    float dinv = rsqrtf((float)degi[i] + 1.0f);
#pragma unroll
    for (int d = 0; d < D; ++d) {
        float acc = 0.0f;
#pragma unroll
        for (int k = 0; k < D; ++k) acc = fmaf(t[k], sW[k * D + d], acc);
        float v = dinv * acc;
        P[i * D + d] = v;
        if (Qdup) Qdup[i * D + d] = v;
    }
}

__global__ __launch_bounds__(256) void final_kernel(
        const float* __restrict__ Q, const float* __restrict__ st, float invN,
        const float* __restrict__ g, const float* __restrict__ be,
        const float* __restrict__ Wm1, const float* __restrict__ bm1,
        const float* __restrict__ Wm2, const float* __restrict__ bm2,
        float* __restrict__ out, int N) {
    __shared__ float sW1[D * 12];
    __shared__ float sb1[12], sW2[12];
    __shared__ float sScale[D], sShift[D];
    __shared__ float sb2;
    for (int j = threadIdx.x; j < D * 12; j += blockDim.x) sW1[j] = Wm1[j];
    if (threadIdx.x < 12) {
        sb1[threadIdx.x] = bm1[threadIdx.x];
        sW2[threadIdx.x] = Wm2[threadIdx.x];
    }
    if (threadIdx.x < D) {
        float m = st[threadIdx.x] * invN;
        float v = fmaxf(st[D + threadIdx.x] * invN - m * m, 0.0f);
        float sc = rsqrtf(v + EPS) * g[threadIdx.x];
        sScale[threadIdx.x] = sc;
        sShift[threadIdx.x] = be[threadIdx.x] - m * sc;
    }
    if (threadIdx.x == 0) sb2 = bm2[0];
    __syncthreads();
    int i = blockIdx.x * blockDim.x + threadIdx.x;
    if (i >= N) return;
    float t[D];
#pragma unroll
    for (int d = 0; d < D; ++d)
        t[d] = fmaxf(0.0f, fmaf(Q[i * D + d], sScale[d], sShift[d]));
    float z = sb2;
#pragma unroll
    for (int j = 0; j < 12; ++j) {
        float m = sb1[j];
#pragma unroll
        for (int k = 0; k < D; ++k) m = fmaf(t[k], sW1[k * 12 + j], m);
        m = fmaxf(0.0f, m);
        z = fmaf(m, sW2[j], z);
    }
    out[i] = 1.0f / (1.0f + expf(-z));
}

extern "C" void kernel_launch(void* const* d_in, const int* in_sizes, int n_in,
                              void* d_out, int out_size, void* d_ws, size_t ws_size,
                              hipStream_t stream) {
    const int*   x    = (const int*)d_in[0];
    const int*   ei   = (const int*)d_in[1];
    const float* emb  = (const float*)d_in[2];
    const float* W1   = (const float*)d_in[3];
    const float* b1   = (const float*)d_in[4];
    const float* g1   = (const float*)d_in[5];
    const float* be1  = (const float*)d_in[6];
    const float* W2   = (const float*)d_in[7];
    const float* b2   = (const float*)d_in[8];
    const float* g2   = (const float*)d_in[9];
    const float* be2  = (const float*)d_in[10];
    const float* Wm1  = (const float*)d_in[11];
    const float* bm1  = (const float*)d_in[12];
    const float* Wm2  = (const float*)d_in[13];
    const float* bm2  = (const float*)d_in[14];
    float* out = (float*)d_out;

    int N = in_sizes[0];
    int E = in_sizes[1] / 2;
    const int* src = ei;
    const int* dst = ei + E;
    float invN = 1.0f / (float)N;
    int Nhalf = N / 2;

    int nbBin = (E + BIN_EDGES - 1) / BIN_EDGES;
    // words: degi N + cursor N + mid N + csr E + bCount 512 + hist2D nbBin*512
    //        + P8 8N + Qh 16N + stPart 6400 + align slack
    size_t csrNeed = ((size_t)27 * N + E + 512 + (size_t)nbBin * NBKT +
                      2 * NSLOT * 50 + 16) * 4;
    bool useCSR = (ws_size >= csrNeed) && (N <= NBKT * 512) && (nbBin <= 512) &&
                  ((size_t)E <= (size_t)16 * N) && (nbBin >= 25);

    int nbN  = (N + 255) / 256;
    int nbE  = (E + 255) / 256;
    int nbG  = (N + 31) / 32;            // fallback gather grid
    int nbS  = (int)(((long)E * 32 + 255) / 256);

    if (useCSR) {
        int*    degi    = (int*)d_ws;                   // N
        int*    cursor  = degi + N;                     // N
        int*    mid     = cursor + N;                   // N
        int*    csr     = mid + N;                      // E
        int*    bCount  = csr + E;                      // 512
        int*    hist2D  = bCount + NBKT;                // nbBin*512
        int*    hEnd    = hist2D + (size_t)nbBin * NBKT;
        u32*    P8      = (u32*)(((uintptr_t)hEnd + 15) & ~(uintptr_t)15); // 8N dwords (N rows x 32 B)
        __half* Qh      = (__half*)(P8 + 8 * (size_t)N);                   // 32N halves = 16N dwords
        float*  stP1    = (float*)((u32*)Qh + 16 * (size_t)N);             // 64*50
        float*  stP2    = stP1 + NSLOT * 50;                               // 64*50
        int*    binned  = (int*)Qh;   // E ints (aliases Qh; dead before Qh written; E<=16N)

        int nbBkt = (N + 511) / 512;

        binA<<<nbBin, 256, 0, stream>>>(dst, hist2D, stP1, E);
        colscan<<<NBKT, 512, 0, stream>>>(hist2D, bCount, nbBin);
        binB<<<nbBin, 512, 0, stream>>>(src, dst, hist2D, bCount, binned, E);
        bucket_fill<<<nbBkt, 512, 0, stream>>>(binned, bCount, degi, cursor, mid, csr, N, Nhalf);
        embed_gemm1_q8<<<nbN, 256, 0, stream>>>(x, emb, W1, degi, P8, N);
        {
            const float* bb = b1;
            void* args[] = {(void*)&csr, (void*)&cursor, (void*)&mid, (void*)&degi,
                            (void*)&P8, (void*)&bb, (void*)&Qh, (void*)&stP1,
                            (void*)&N, (void*)&Nhalf};
            if (hipLaunchCooperativeKernel((const void*)gather_coop, dim3(GBLK),
                                           dim3(256), args, 0, stream) != hipSuccess)
                gather_stats_q8<<<nbG, 256, 0, stream>>>(csr, cursor, degi, P8, b1, Qh, stP1, N);
        }
        bn_gemm_q8<<<nbN, 256, 0, stream>>>(Qh, stP1, invN, g1, be1, W2, degi, P8, N);
        {
            const float* bb = b2;
            void* args[] = {(void*)&csr, (void*)&cursor, (void*)&mid, (void*)&degi,
                            (void*)&P8, (void*)&bb, (void*)&Qh, (void*)&stP2,
                            (void*)&N, (void*)&Nhalf};
            if (hipLaunchCooperativeKernel((const void*)gather_coop, dim3(GBLK),
                                           dim3(256), args, 0, stream) != hipSuccess)
                gather_stats_q8<<<nbG, 256, 0, stream>>>(csr, cursor, degi, P8, b2, Qh, stP2, N);
        }
        final_kernel_p<<<nbN, 256, 0, stream>>>(Qh, stP2, invN, g2, be2, Wm1, bm1, Wm2, bm2, out, N);
    } else {
        // fallback: fp32 atomic-scatter path
        int*   degi  = (int*)d_ws;                  // N
        float* P     = (float*)(degi + N);          // N*D
        float* Q     = P + (size_t)N * D;           // N*D
        float* stats = Q + (size_t)N * D;           // 100
        float* st1 = stats;
        float* st2 = stats + 50;

        hipMemsetAsync(degi, 0, (size_t)N * sizeof(int), stream);
        hipMemsetAsync(stats, 0, 100 * sizeof(float), stream);

        hist_kernel<<<nbE, 256, 0, stream>>>(dst, degi, E);
        embed_gemm1<<<nbN, 256, 0, stream>>>(x, emb, W1, degi, P, Q, N);
        scatter_kernel<<<nbS, 256, 0, stream>>>(src, dst, P, Q, E);
        transform_kernel<<<nbN, 256, 0, stream>>>(Q, degi, b1, N);
        stats_kernel<<<STATS_BLOCKS, 256, 0, stream>>>(Q, st1, N);
        bn_gemm<<<nbN, 256, 0, stream>>>(Q, st1, invN, g1, be1, W2, degi, P, Q, N);
        scatter_kernel<<<nbS, 256, 0, stream>>>(src, dst, P, Q, E);
        transform_kernel<<<nbN, 256, 0, stream>>>(Q, degi, b2, N);
        stats_kernel<<<STATS_BLOCKS, 256, 0, stream>>>(Q, st2, N);
        final_kernel<<<nbN, 256, 0, stream>>>(Q, st2, invN, g2, be2, Wm1, bm1, Wm2, bm2, out, N);
    }
}

// Round 5
// 651.291 us; speedup vs baseline: 2.8329x; 2.8329x over previous
//
#include <hip/hip_runtime.h>
#include <hip/hip_fp16.h>
#include <hip/hip_cooperative_groups.h>
#include <math.h>

namespace cg = cooperative_groups;

#define D 25
#define STATS_BLOCKS 512
#define NBKT 512        // buckets of 512 nodes
#define BSH 9
#define BMSK 511
#define BIN_EDGES 8192  // edges per bin block
#define SORT_CAP 10240  // LDS sort capacity per bucket (avg ~8.2k)
#define NSLOT 64        // replicated stat partial slots
#define GBLK 1024       // cooperative gather grid (256 CU x 4 blocks, guaranteed resident)
#define NPB 8           // node-group batches per block: 1024*8*32 = 262144 >= N cap
#define EPS 1e-5f

typedef unsigned int u32;
typedef unsigned long long u64;

// ---------------- binA: per-(block,bucket) histogram + stPart zeroing ----------------
__global__ __launch_bounds__(256) void binA(const int* __restrict__ dst,
                                            int* __restrict__ hist2D,
                                            float* __restrict__ stPart, int E) {
    if (blockIdx.x < 25) stPart[blockIdx.x * 256 + threadIdx.x] = 0.0f;
    __shared__ int h[NBKT];
    h[threadIdx.x] = 0;
    h[threadIdx.x + 256] = 0;
    __syncthreads();
    int base = blockIdx.x * BIN_EDGES;
#pragma unroll
    for (int j = 0; j < 32; ++j) {
        int idx = base + j * 256 + threadIdx.x;
        if (idx < E) atomicAdd(&h[dst[idx] >> BSH], 1);
    }
    __syncthreads();
    hist2D[blockIdx.x * NBKT + threadIdx.x] = h[threadIdx.x];
    hist2D[blockIdx.x * NBKT + threadIdx.x + 256] = h[threadIdx.x + 256];
}

// ------- colscan: per bucket, exclusive scan over blocks (in place) + total -------
__global__ __launch_bounds__(512) void colscan(int* __restrict__ hist2D,
                                               int* __restrict__ bCount, int nbBin) {
    __shared__ int s[512];
    int b = blockIdx.x;
    int j = threadIdx.x;
    int v = (j < nbBin) ? hist2D[j * NBKT + b] : 0;
    s[j] = v;
    __syncthreads();
    for (int off = 1; off < 512; off <<= 1) {
        int x = (j >= off) ? s[j - off] : 0;
        __syncthreads();
        s[j] += x;
        __syncthreads();
    }
    if (j < nbBin) hist2D[j * NBKT + b] = s[j] - v;   // exclusive prefix
    if (j == 0) bCount[b] = s[511];
}

// ------- binB (512 thr): inline scan of bCount for bases; write keys grouped by bucket -------
__global__ __launch_bounds__(512) void binB(const int* __restrict__ src,
                                            const int* __restrict__ dst,
                                            const int* __restrict__ hist2D,
                                            const int* __restrict__ bCount,
                                            int* __restrict__ binned, int E) {
    __shared__ int rank[NBKT], basew[NBKT], sc[NBKT];
    int t = threadIdx.x;
    int cnt = bCount[t];
    sc[t] = cnt;
    rank[t] = 0;
    __syncthreads();
    for (int off = 1; off < NBKT; off <<= 1) {
        int x = (t >= off) ? sc[t - off] : 0;
        __syncthreads();
        sc[t] += x;
        __syncthreads();
    }
    basew[t] = (sc[t] - cnt) + hist2D[blockIdx.x * NBKT + t];
    __syncthreads();
    int base = blockIdx.x * BIN_EDGES;
#pragma unroll
    for (int j = 0; j < 16; ++j) {
        int idx = base + j * 512 + t;
        if (idx < E) {
            int d = dst[idx];
            int b = d >> BSH;
            int r = atomicAdd(&rank[b], 1);
            binned[basew[b] + r] = (src[idx] << BSH) | (d & BMSK);
        }
    }
}

// ------- bucket_fill (512 thr): sort bucket b (512 nodes) in LDS; each row partitioned
//         [src < Nhalf | src >= Nhalf]; mid[node] = global start of the high part -------
__global__ __launch_bounds__(512) void bucket_fill(
        const int* __restrict__ binned, const int* __restrict__ bCount,
        int* __restrict__ degi, int* __restrict__ cursor, int* __restrict__ mid,
        int* __restrict__ csr, int N, int Nhalf) {
    int b = blockIdx.x;
    int nodeBase = b << BSH;
    if (nodeBase >= N) return;
    __shared__ int h[NBKT];      // low histogram / low write-cursor
    __shared__ int hHi[NBKT];    // high histogram / high write-cursor
    __shared__ int s2[512];
    __shared__ int sorted[SORT_CAP];
    int t = threadIdx.x;
    // parallel reduce of bCount[0..b-1] into base
    s2[t] = (t < b) ? bCount[t] : 0;
    __syncthreads();
    for (int off = 256; off > 0; off >>= 1) {
        if (t < off) s2[t] += s2[t + off];
        __syncthreads();
    }
    int s = s2[0];
    __syncthreads();
    h[t] = 0;
    hHi[t] = 0;
    __syncthreads();
    int cnt = bCount[b];
    int e = s + cnt;
    // per-(node, src-half) degree histogram
    for (int k = s + t; k < e; k += 512) {
        int key = binned[k];
        if ((key >> BSH) >= Nhalf) atomicAdd(&hHi[key & BMSK], 1);
        else                       atomicAdd(&h[key & BMSK], 1);
    }
    __syncthreads();
    int lo = h[t], hc = hHi[t];
    int dg = lo + hc;
    int node = nodeBase + t;
    if (node < N) degi[node] = dg;
    s2[t] = dg;
    __syncthreads();
    for (int off = 1; off < 512; off <<= 1) {
        int x = (t >= off) ? s2[t - off] : 0;
        __syncthreads();
        s2[t] += x;
        __syncthreads();
    }
    int rowstart = s2[t] - dg;         // local row start
    if (node < N) {
        cursor[node] = s + s2[t];      // global row end
        mid[node]    = s + rowstart + lo;  // global start of high-src part
    }
    h[t]   = rowstart;                 // low write-cursor (local)
    hHi[t] = rowstart + lo;            // high write-cursor (local)
    __syncthreads();
    if (cnt <= SORT_CAP) {
        // scatter into LDS, then coalesced writeout
        for (int k = s + t; k < e; k += 512) {
            int key = binned[k];
            int bb = key & BMSK;
            int p = ((key >> BSH) >= Nhalf) ? atomicAdd(&hHi[bb], 1)
                                            : atomicAdd(&h[bb], 1);
            sorted[p] = key >> BSH;
        }
        __syncthreads();
        for (int j = t; j < cnt; j += 512)
            csr[s + j] = sorted[j];
    } else {
        // overflow fallback: direct global scatter
        for (int k = s + t; k < e; k += 512) {
            int key = binned[k];
            int bb = key & BMSK;
            int p = ((key >> BSH) >= Nhalf) ? atomicAdd(&hHi[bb], 1)
                                            : atomicAdd(&h[bb], 1);
            csr[s + p] = key >> BSH;
        }
    }
}

// ================= int8-quantized row format =================
// row = 32 B: dwords 0..6 hold 25 int8 (bytes 25..27 zero), dword 7 = fp32 scale.
// value[d] = (int8)byte[d] * scale.  scale = rowmax/127, round-to-nearest.

__device__ __forceinline__ void quant_store_q8(u32* __restrict__ P8, int i,
                                               const float* v) {
    float mx = 0.0f;
#pragma unroll
    for (int d = 0; d < D; ++d) mx = fmaxf(mx, fabsf(v[d]));
    float scale = mx * (1.0f / 127.0f);
    float inv = (mx > 0.0f) ? (127.0f / mx) : 0.0f;
    u32 w[8];
#pragma unroll
    for (int dw = 0; dw < 7; ++dw) {
        u32 p = 0;
#pragma unroll
        for (int j = 0; j < 4; ++j) {
            int d = dw * 4 + j;
            int q = (d < D) ? __float2int_rn(v[d] * inv) : 0;
            p |= ((u32)q & 255u) << (8 * j);
        }
        w[dw] = p;
    }
    w[7] = __float_as_uint(scale);
    uint4* o = (uint4*)(P8 + ((size_t)i << 3));
    o[0] = make_uint4(w[0], w[1], w[2], w[3]);
    o[1] = make_uint4(w[4], w[5], w[6], w[7]);
}

__device__ __forceinline__ void acc_q8(u32 w, float c,
                                       float& a0, float& a1, float& a2, float& a3) {
    a0 = fmaf(c, (float)((int)(w << 24) >> 24), a0);
    a1 = fmaf(c, (float)((int)(w << 16) >> 24), a1);
    a2 = fmaf(c, (float)((int)(w <<  8) >> 24), a2);
    a3 = fmaf(c, (float)((int)w >> 24), a3);
}

// walk edge range [k, end): 8 edges in flight, 8-lane group, lane f = dword of row
__device__ __forceinline__ void walk_q8(const int* __restrict__ csr,
                                        const u32* __restrict__ P8, int k, int end,
                                        int f, float& a0, float& a1, float& a2, float& a3) {
    for (; k + 8 <= end; k += 8) {
        int e0 = __builtin_nontemporal_load(csr + k);
        int e1 = __builtin_nontemporal_load(csr + k + 1);
        int e2 = __builtin_nontemporal_load(csr + k + 2);
        int e3 = __builtin_nontemporal_load(csr + k + 3);
        int e4 = __builtin_nontemporal_load(csr + k + 4);
        int e5 = __builtin_nontemporal_load(csr + k + 5);
        int e6 = __builtin_nontemporal_load(csr + k + 6);
        int e7 = __builtin_nontemporal_load(csr + k + 7);
        u32 w0 = P8[((size_t)e0 << 3) + f];
        u32 w1 = P8[((size_t)e1 << 3) + f];
        u32 w2 = P8[((size_t)e2 << 3) + f];
        u32 w3 = P8[((size_t)e3 << 3) + f];
        u32 w4 = P8[((size_t)e4 << 3) + f];
        u32 w5 = P8[((size_t)e5 << 3) + f];
        u32 w6 = P8[((size_t)e6 << 3) + f];
        u32 w7 = P8[((size_t)e7 << 3) + f];
        float c0 = __shfl(__uint_as_float(w0), 7, 8);
        float c1 = __shfl(__uint_as_float(w1), 7, 8);
        float c2 = __shfl(__uint_as_float(w2), 7, 8);
        float c3 = __shfl(__uint_as_float(w3), 7, 8);
        float c4 = __shfl(__uint_as_float(w4), 7, 8);
        float c5 = __shfl(__uint_as_float(w5), 7, 8);
        float c6 = __shfl(__uint_as_float(w6), 7, 8);
        float c7 = __shfl(__uint_as_float(w7), 7, 8);
        acc_q8(w0, c0, a0, a1, a2, a3);
        acc_q8(w1, c1, a0, a1, a2, a3);
        acc_q8(w2, c2, a0, a1, a2, a3);
        acc_q8(w3, c3, a0, a1, a2, a3);
        acc_q8(w4, c4, a0, a1, a2, a3);
        acc_q8(w5, c5, a0, a1, a2, a3);
        acc_q8(w6, c6, a0, a1, a2, a3);
        acc_q8(w7, c7, a0, a1, a2, a3);
    }
    for (; k < end; ++k) {
        int e = __builtin_nontemporal_load(csr + k);
        u32 w = P8[((size_t)e << 3) + f];
        float c = __shfl(__uint_as_float(w), 7, 8);
        acc_q8(w, c, a0, a1, a2, a3);
    }
}

// ------------- layer1: P8 = q8(dinv * (emb[x] @ W1)) -------------
__global__ __launch_bounds__(256) void embed_gemm1_q8(
        const int* __restrict__ x, const float* __restrict__ emb,
        const float* __restrict__ W1, const int* __restrict__ degi,
        u32* __restrict__ P8, int N) {
    __shared__ float sW[D * D];
    for (int j = threadIdx.x; j < D * D; j += blockDim.x) sW[j] = W1[j];
    __syncthreads();
    int i = blockIdx.x * blockDim.x + threadIdx.x;
    if (i >= N) return;
    const float* er = emb + (size_t)x[i] * D;
    float t[D];
#pragma unroll
    for (int k = 0; k < D; ++k) t[k] = er[k];
    float dinv = rsqrtf((float)degi[i] + 1.0f);
    float v[D];
#pragma unroll
    for (int d = 0; d < D; ++d) {
        float acc = 0.0f;
#pragma unroll
        for (int k = 0; k < D; ++k) acc = fmaf(t[k], sW[k * D + d], acc);
        v[d] = dinv * acc;
    }
    quant_store_q8(P8, i, v);
}

// ------- cooperative phased gather: phase A = src<Nhalf (3.2 MB rows, L2-resident),
//         grid barrier, phase B = src>=Nhalf + bias/dinv + Qh write + BN stats.
//         Inter-phase accumulator state staged in LDS (NOT an indexed per-thread
//         array: round-4's acc[NPB][4] was demoted to scratch -> 2 GB spill traffic).
//         Working accumulator within each batch = 4 named scalars (registers). -------
__global__ __launch_bounds__(256, 4) void gather_coop(
        const int* __restrict__ csr, const int* __restrict__ cursor,
        const int* __restrict__ mid, const int* __restrict__ degi,
        const u32* __restrict__ P8, const float* __restrict__ bias,
        __half* __restrict__ Qh, float* __restrict__ stPart, int N, int Nhalf) {
    __shared__ float4 accS[NPB][256];   // 32 KB: per-batch per-thread partials
    __shared__ float red[4][8][8];
    int t = threadIdx.x;
    int f = t & 7;
    int grp = t >> 3;
    cg::grid_group grid = cg::this_grid();
    // ---- phase A: low-src halves only (row working set = Nhalf*32B, L2-resident) ----
#pragma unroll
    for (int b = 0; b < NPB; ++b) {
        float a0 = 0.f, a1 = 0.f, a2 = 0.f, a3 = 0.f;
        int node = (blockIdx.x + b * gridDim.x) * 32 + grp;
        if (node < N) {
            int end = cursor[node];
            int m   = mid[node];
            int k   = end - degi[node];
            if (node < Nhalf) {   // self loop lives in the low half
                u32 w = P8[((size_t)node << 3) + f];
                float c = __shfl(__uint_as_float(w), 7, 8);
                acc_q8(w, c, a0, a1, a2, a3);
            }
            walk_q8(csr, P8, k, m, f, a0, a1, a2, a3);
        }
        accS[b][t] = make_float4(a0, a1, a2, a3);
    }
    grid.sync();
    // ---- phase B: high-src halves + epilogue ----
    float r0 = 0, r1 = 0, r2 = 0, r3 = 0, r4 = 0, r5 = 0, r6 = 0, r7 = 0;
#pragma unroll
    for (int b = 0; b < NPB; ++b) {
        float4 av = accS[b][t];
        float a0 = av.x, a1 = av.y, a2 = av.z, a3 = av.w;
        int node = (blockIdx.x + b * gridDim.x) * 32 + grp;
        float q0 = 0.f, q1 = 0.f, q2 = 0.f, q3 = 0.f;
        if (node < N) {
            int end = cursor[node];
            int m   = mid[node];
            if (node >= Nhalf) {
                u32 w = P8[((size_t)node << 3) + f];
                float c = __shfl(__uint_as_float(w), 7, 8);
                acc_q8(w, c, a0, a1, a2, a3);
            }
            walk_q8(csr, P8, m, end, f, a0, a1, a2, a3);
            float dinv = rsqrtf((float)degi[node] + 1.0f);
            int j0 = f << 2;
            if (f < 7) {
                q0 = fmaf(dinv, a0, bias[j0]);
                if (j0 + 1 < D) q1 = fmaf(dinv, a1, bias[j0 + 1]);
                if (j0 + 2 < D) q2 = fmaf(dinv, a2, bias[j0 + 2]);
                if (j0 + 3 < D) q3 = fmaf(dinv, a3, bias[j0 + 3]);
            }
            __half2 h01 = __floats2half2_rn(q0, q1);
            __half2 h23 = __floats2half2_rn(q2, q3);
            union { __half2 h[2]; u64 u; } cv;
            cv.h[0] = h01; cv.h[1] = h23;
            __builtin_nontemporal_store(cv.u, (u64*)Qh + ((size_t)node << 3) + f);
        }
        r0 += q0; r1 += q1; r2 += q2; r3 += q3;
        r4 += q0 * q0; r5 += q1 * q1; r6 += q2 * q2; r7 += q3 * q3;
    }
    // ---- fused BN stats ----
    float r[8] = {r0, r1, r2, r3, r4, r5, r6, r7};
#pragma unroll
    for (int v = 0; v < 8; ++v) {
        r[v] += __shfl_down(r[v], 32, 64);
        r[v] += __shfl_down(r[v], 16, 64);
        r[v] += __shfl_down(r[v], 8, 64);
    }
    int wv = t >> 6;
    if ((t & 63) < 8) {
#pragma unroll
        for (int v = 0; v < 8; ++v) red[wv][f][v] = r[v];
    }
    __syncthreads();
    if (t < 64) {
        int ff = t >> 3, v = t & 7;
        float tot = red[0][ff][v] + red[1][ff][v] + red[2][ff][v] + red[3][ff][v];
        int a = (ff << 2) + (v & 3);
        if (a < D)
            atomicAdd(&stPart[(blockIdx.x & (NSLOT - 1)) * 50 + (v >> 2) * D + a], tot);
    }
}

// ------- non-coop fallback gather (Round-3 verified kernel) -------
__global__ __launch_bounds__(256) void gather_stats_q8(
        const int* __restrict__ csr, const int* __restrict__ cursor,
        const int* __restrict__ degi, const u32* __restrict__ P8,
        const float* __restrict__ bias, __half* __restrict__ Qh,
        float* __restrict__ stPart, int N) {
    __shared__ float red[4][8][8];
    int t = threadIdx.x;
    int node = blockIdx.x * 32 + (t >> 3);
    int f = t & 7;
    float a0 = 0.f, a1 = 0.f, a2 = 0.f, a3 = 0.f;
    float q0 = 0.f, q1 = 0.f, q2 = 0.f, q3 = 0.f;
    if (node < N) {
        int end = cursor[node];
        int dg  = degi[node];
        int k = end - dg;
        u32 wsf = P8[((size_t)node << 3) + f];
        float csf = __shfl(__uint_as_float(wsf), 7, 8);
        acc_q8(wsf, csf, a0, a1, a2, a3);
        walk_q8(csr, P8, k, end, f, a0, a1, a2, a3);
        float dinv = rsqrtf((float)dg + 1.0f);
        int j0 = f << 2;
        if (f < 7) {
            q0 = fmaf(dinv, a0, bias[j0]);
            if (j0 + 1 < D) q1 = fmaf(dinv, a1, bias[j0 + 1]);
            if (j0 + 2 < D) q2 = fmaf(dinv, a2, bias[j0 + 2]);
            if (j0 + 3 < D) q3 = fmaf(dinv, a3, bias[j0 + 3]);
        }
        __half2 h01 = __floats2half2_rn(q0, q1);
        __half2 h23 = __floats2half2_rn(q2, q3);
        union { __half2 h[2]; u64 u; } cv;
        cv.h[0] = h01; cv.h[1] = h23;
        __builtin_nontemporal_store(cv.u, (u64*)Qh + ((size_t)node << 3) + f);
    }
    float r[8] = {q0, q1, q2, q3, q0 * q0, q1 * q1, q2 * q2, q3 * q3};
#pragma unroll
    for (int v = 0; v < 8; ++v) {
        r[v] += __shfl_down(r[v], 32, 64);
        r[v] += __shfl_down(r[v], 16, 64);
        r[v] += __shfl_down(r[v], 8, 64);
    }
    int wv = t >> 6;
    if ((t & 63) < 8) {
#pragma unroll
        for (int v = 0; v < 8; ++v) red[wv][f][v] = r[v];
    }
    __syncthreads();
    if (t < 64) {
        int ff = t >> 3, v = t & 7;
        float tot = red[0][ff][v] + red[1][ff][v] + red[2][ff][v] + red[3][ff][v];
        int a = (ff << 2) + (v & 3);
        if (a < D)
            atomicAdd(&stPart[(blockIdx.x & (NSLOT - 1)) * 50 + (v >> 2) * D + a], tot);
    }
}

// ------- layer2: reduce stPart -> mu/rstd; t = relu(bn(Qh)); P8 = q8(dinv*(t@W2)) -------
__global__ __launch_bounds__(256) void bn_gemm_q8(
        const __half* __restrict__ Qh, const float* __restrict__ stPart, float invN,
        const float* __restrict__ g, const float* __restrict__ be,
        const float* __restrict__ W, const int* __restrict__ degi,
        u32* __restrict__ P8, int N) {
    __shared__ float sW[D * D];
    __shared__ float sScale[D], sShift[D];
    __shared__ float sSum[2 * D];
    for (int j = threadIdx.x; j < D * D; j += blockDim.x) sW[j] = W[j];
    if (threadIdx.x < 2 * D) {
        float a = 0.0f;
        for (int k = 0; k < NSLOT; ++k) a += stPart[k * 50 + threadIdx.x];
        sSum[threadIdx.x] = a;
    }
    __syncthreads();
    if (threadIdx.x < D) {
        float m = sSum[threadIdx.x] * invN;
        float v = fmaxf(sSum[D + threadIdx.x] * invN - m * m, 0.0f);
        float sc = rsqrtf(v + EPS) * g[threadIdx.x];
        sScale[threadIdx.x] = sc;
        sShift[threadIdx.x] = be[threadIdx.x] - m * sc;
    }
    __syncthreads();
    int i = blockIdx.x * blockDim.x + threadIdx.x;
    if (i >= N) return;
    const __half2* qrow = (const __half2*)Qh + ((size_t)i << 4);
    float t[D];
#pragma unroll
    for (int ff = 0; ff < 13; ++ff) {
        float2 v = __half22float2(qrow[ff]);
        int j0 = ff << 1;
        t[j0] = fmaxf(0.0f, fmaf(v.x, sScale[j0], sShift[j0]));
        if (ff < 12) t[j0 + 1] = fmaxf(0.0f, fmaf(v.y, sScale[j0 + 1], sShift[j0 + 1]));
    }
    float dinv = rsqrtf((float)degi[i] + 1.0f);
    float vout[D];
#pragma unroll
    for (int d = 0; d < D; ++d) {
        float acc = 0.0f;
#pragma unroll
        for (int k = 0; k < D; ++k) acc = fmaf(t[k], sW[k * D + d], acc);
        vout[d] = dinv * acc;
    }
    quant_store_q8(P8, i, vout);
}

// ------- head: reduce stPart -> mu/rstd; t = relu(bn(Qh)); MLP; sigmoid -------
__global__ __launch_bounds__(256) void final_kernel_p(
        const __half* __restrict__ Qh, const float* __restrict__ stPart, float invN,
        const float* __restrict__ g, const float* __restrict__ be,
        const float* __restrict__ Wm1, const float* __restrict__ bm1,
        const float* __restrict__ Wm2, const float* __restrict__ bm2,
        float* __restrict__ out, int N) {
    __shared__ float sW1[D * 12];
    __shared__ float sb1[12], sW2[12];
    __shared__ float sScale[D], sShift[D];
    __shared__ float sSum[2 * D];
    __shared__ float sb2;
    for (int j = threadIdx.x; j < D * 12; j += blockDim.x) sW1[j] = Wm1[j];
    if (threadIdx.x < 12) {
        sb1[threadIdx.x] = bm1[threadIdx.x];
        sW2[threadIdx.x] = Wm2[threadIdx.x];
    }
    if (threadIdx.x < 2 * D) {
        float a = 0.0f;
        for (int k = 0; k < NSLOT; ++k) a += stPart[k * 50 + threadIdx.x];
        sSum[threadIdx.x] = a;
    }
    if (threadIdx.x == 0) sb2 = bm2[0];
    __syncthreads();
    if (threadIdx.x < D) {
        float m = sSum[threadIdx.x] * invN;
        float v = fmaxf(sSum[D + threadIdx.x] * invN - m * m, 0.0f);
        float sc = rsqrtf(v + EPS) * g[threadIdx.x];
        sScale[threadIdx.x] = sc;
        sShift[threadIdx.x] = be[threadIdx.x] - m * sc;
    }
    __syncthreads();
    int i = blockIdx.x * blockDim.x + threadIdx.x;
    if (i >= N) return;
    const __half2* qrow = (const __half2*)Qh + ((size_t)i << 4);
    float t[D];
#pragma unroll
    for (int ff = 0; ff < 13; ++ff) {
        float2 v = __half22float2(qrow[ff]);
        int j0 = ff << 1;
        t[j0] = fmaxf(0.0f, fmaf(v.x, sScale[j0], sShift[j0]));
        if (ff < 12) t[j0 + 1] = fmaxf(0.0f, fmaf(v.y, sScale[j0 + 1], sShift[j0 + 1]));
    }
    float z = sb2;
#pragma unroll
    for (int j = 0; j < 12; ++j) {
        float m = sb1[j];
#pragma unroll
        for (int k = 0; k < D; ++k) m = fmaf(t[k], sW1[k * 12 + j], m);
        m = fmaxf(0.0f, m);
        z = fmaf(m, sW2[j], z);
    }
    out[i] = 1.0f / (1.0f + expf(-z));
}

// ================= fallback kernels (atomic-scatter path, fp32) =================
__global__ void hist_kernel(const int* __restrict__ dst, int* __restrict__ degi, int E) {
    int e = blockIdx.x * blockDim.x + threadIdx.x;
    if (e < E) atomicAdd(&degi[dst[e]], 1);
}

__global__ __launch_bounds__(256) void embed_gemm1(
        const int* __restrict__ x, const float* __restrict__ emb,
        const float* __restrict__ W1, const int* __restrict__ degi,
        float* __restrict__ P, float* __restrict__ Qdup, int N) {
    __shared__ float sW[D * D];
    for (int j = threadIdx.x; j < D * D; j += blockDim.x) sW[j] = W1[j];
    __syncthreads();
    int i = blockIdx.x * blockDim.x + threadIdx.x;
    if (i >= N) return;
    const float* er = emb + (size_t)x[i] * D;
    float t[D];
#pragma unroll
    for (int k = 0; k < D; ++k) t[k] = er[k];
    float dinv = rsqrtf((float)degi[i] + 1.0f);
#pragma unroll
    for (int d = 0; d < D; ++d) {
        float acc = 0.0f;
#pragma unroll
        for (int k = 0; k < D; ++k) acc = fmaf(t[k], sW[k * D + d], acc);
        float v = dinv * acc;
        P[i * D + d] = v;
        if (Qdup) Qdup[i * D + d] = v;
    }
}

__global__ void scatter_kernel(const int* __restrict__ src, const int* __restrict__ dst,
                               const float* __restrict__ A, float* __restrict__ B, int E) {
    int idx = blockIdx.x * blockDim.x + threadIdx.x;
    int e = idx >> 5;
    int lane = idx & 31;
    if (e >= E || lane >= D) return;
    atomicAdd(&B[dst[e] * D + lane], A[src[e] * D + lane]);
}

__global__ __launch_bounds__(256) void transform_kernel(
        float* __restrict__ Q, const int* __restrict__ degi,
        const float* __restrict__ bias, int N) {
    int i = blockIdx.x * blockDim.x + threadIdx.x;
    if (i >= N) return;
    float dinv = rsqrtf((float)degi[i] + 1.0f);
#pragma unroll
    for (int d = 0; d < D; ++d)
        Q[i * D + d] = fmaf(dinv, Q[i * D + d], bias[d]);
}

__global__ __launch_bounds__(256) void stats_kernel(
        const float* __restrict__ Q, float* __restrict__ st, int N) {
    float ls[D], lq[D];
#pragma unroll
    for (int d = 0; d < D; ++d) { ls[d] = 0.0f; lq[d] = 0.0f; }
    for (int i = blockIdx.x * blockDim.x + threadIdx.x; i < N;
         i += gridDim.x * blockDim.x) {
#pragma unroll
        for (int d = 0; d < D; ++d) {
            float v = Q[i * D + d];
            ls[d] += v;
            lq[d] += v * v;
        }
    }
#pragma unroll
    for (int d = 0; d < D; ++d) {
        for (int off = 32; off > 0; off >>= 1) {
            ls[d] += __shfl_down(ls[d], off, 64);
            lq[d] += __shfl_down(lq[d], off, 64);
        }
    }
    __shared__ float red[4][2 * D];
    int wave = threadIdx.x >> 6;
    int lane = threadIdx.x & 63;
    if (lane == 0) {
#pragma unroll
        for (int d = 0; d < D; ++d) {
            red[wave][d] = ls[d];
            red[wave][D + d] = lq[d];
        }
    }
    __syncthreads();
    if (threadIdx.x < 2 * D) {
        float t = red[0][threadIdx.x] + red[1][threadIdx.x] +
                  red[2][threadIdx.x] + red[3][threadIdx.x];
        atomicAdd(&st[threadIdx.x], t);
    }
}

__global__ __launch_bounds__(256) void bn_gemm(
        const float* __restrict__ Qin, const float* __restrict__ st, float invN,
        const float* __restrict__ g, const float* __restrict__ be,
        const float* __restrict__ W, const int* __restrict__ degi,
        float* __restrict__ P, float* __restrict__ Qdup, int N) {
    __shared__ float sW[D * D];
    __shared__ float sScale[D], sShift[D];
    for (int j = threadIdx.x; j < D * D; j += blockDim.x) sW[j] = W[j];
    if (threadIdx.x < D) {
        float m = st[threadIdx.x] * invN;
        float v = fmaxf(st[D + threadIdx.x] * invN - m * m, 0.0f);
        float sc = rsqrtf(v + EPS) * g[threadIdx.x];
        sScale[threadIdx.x] = sc;
        sShift[threadIdx.x] = be[threadIdx.x] - m * sc;
    }
    __syncthreads();
    int i = blockIdx.x * blockDim.x + threadIdx.x;
    if (i >= N) return;
    float t[D];
#pragma unroll
    for (int d = 0; d < D; ++d)
        t[d] = fmaxf(0.0f, fmaf(Qin[i * D + d], sScale[d], sShift[d]));
    float dinv = rsqrtf((float)degi[i] + 1.0f);
#pragma unroll
    for (int d = 0; d < D; ++d) {
        float acc = 0.0f;
#pragma unroll
        for (int k = 0; k < D; ++k) acc = fmaf(t[k], sW[k * D + d], acc);
        float v = dinv * acc;
        P[i * D + d] = v;
        if (Qdup) Qdup[i * D + d] = v;
    }
}

__global__ __launch_bounds__(256) void final_kernel(
        const float* __restrict__ Q, const float* __restrict__ st, float invN,
        const float* __restrict__ g, const float* __restrict__ be,
        const float* __restrict__ Wm1, const float* __restrict__ bm1,
        const float* __restrict__ Wm2, const float* __restrict__ bm2,
        float* __restrict__ out, int N) {
    __shared__ float sW1[D * 12];
    __shared__ float sb1[12], sW2[12];
    __shared__ float sScale[D], sShift[D];
    __shared__ float sb2;
    for (int j = threadIdx.x; j < D * 12; j += blockDim.x) sW1[j] = Wm1[j];
    if (threadIdx.x < 12) {
        sb1[threadIdx.x] = bm1[threadIdx.x];
        sW2[threadIdx.x] = Wm2[threadIdx.x];
    }
    if (threadIdx.x < D) {
        float m = st[threadIdx.x] * invN;
        float v = fmaxf(st[D + threadIdx.x] * invN - m * m, 0.0f);
        float sc = rsqrtf(v + EPS) * g[threadIdx.x];
        sScale[threadIdx.x] = sc;
        sShift[threadIdx.x] = be[threadIdx.x] - m * sc;
    }
    if (threadIdx.x == 0) sb2 = bm2[0];
    __syncthreads();
    int i = blockIdx.x * blockDim.x + threadIdx.x;
    if (i >= N) return;
    float t[D];
#pragma unroll
    for (int d = 0; d < D; ++d)
        t[d] = fmaxf(0.0f, fmaf(Q[i * D + d], sScale[d], sShift[d]));
    float z = sb2;
#pragma unroll
    for (int j = 0; j < 12; ++j) {
        float m = sb1[j];
#pragma unroll
        for (int k = 0; k < D; ++k) m = fmaf(t[k], sW1[k * 12 + j], m);
        m = fmaxf(0.0f, m);
        z = fmaf(m, sW2[j], z);
    }
    out[i] = 1.0f / (1.0f + expf(-z));
}

extern "C" void kernel_launch(void* const* d_in, const int* in_sizes, int n_in,
                              void* d_out, int out_size, void* d_ws, size_t ws_size,
                              hipStream_t stream) {
    const int*   x    = (const int*)d_in[0];
    const int*   ei   = (const int*)d_in[1];
    const float* emb  = (const float*)d_in[2];
    const float* W1   = (const float*)d_in[3];
    const float* b1   = (const float*)d_in[4];
    const float* g1   = (const float*)d_in[5];
    const float* be1  = (const float*)d_in[6];
    const float* W2   = (const float*)d_in[7];
    const float* b2   = (const float*)d_in[8];
    const float* g2   = (const float*)d_in[9];
    const float* be2  = (const float*)d_in[10];
    const float* Wm1  = (const float*)d_in[11];
    const float* bm1  = (const float*)d_in[12];
    const float* Wm2  = (const float*)d_in[13];
    const float* bm2  = (const float*)d_in[14];
    float* out = (float*)d_out;

    int N = in_sizes[0];
    int E = in_sizes[1] / 2;
    const int* src = ei;
    const int* dst = ei + E;
    float invN = 1.0f / (float)N;
    int Nhalf = N / 2;

    int nbBin = (E + BIN_EDGES - 1) / BIN_EDGES;
    // words: degi N + cursor N + mid N + csr E + bCount 512 + hist2D nbBin*512
    //        + P8 8N + Qh 16N + stPart 6400 + align slack
    size_t csrNeed = ((size_t)27 * N + E + 512 + (size_t)nbBin * NBKT +
                      2 * NSLOT * 50 + 16) * 4;
    bool useCSR = (ws_size >= csrNeed) && (N <= NBKT * 512) && (nbBin <= 512) &&
                  ((size_t)E <= (size_t)16 * N) && (nbBin >= 25);

    int nbN  = (N + 255) / 256;
    int nbE  = (E + 255) / 256;
    int nbG  = (N + 31) / 32;            // fallback gather grid
    int nbS  = (int)(((long)E * 32 + 255) / 256);

    if (useCSR) {
        int*    degi    = (int*)d_ws;                   // N
        int*    cursor  = degi + N;                     // N
        int*    mid     = cursor + N;                   // N
        int*    csr     = mid + N;                      // E
        int*    bCount  = csr + E;                      // 512
        int*    hist2D  = bCount + NBKT;                // nbBin*512
        int*    hEnd    = hist2D + (size_t)nbBin * NBKT;
        u32*    P8      = (u32*)(((uintptr_t)hEnd + 15) & ~(uintptr_t)15); // 8N dwords (N rows x 32 B)
        __half* Qh      = (__half*)(P8 + 8 * (size_t)N);                   // 32N halves = 16N dwords
        float*  stP1    = (float*)((u32*)Qh + 16 * (size_t)N);             // 64*50
        float*  stP2    = stP1 + NSLOT * 50;                               // 64*50
        int*    binned  = (int*)Qh;   // E ints (aliases Qh; dead before Qh written; E<=16N)

        int nbBkt = (N + 511) / 512;

        binA<<<nbBin, 256, 0, stream>>>(dst, hist2D, stP1, E);
        colscan<<<NBKT, 512, 0, stream>>>(hist2D, bCount, nbBin);
        binB<<<nbBin, 512, 0, stream>>>(src, dst, hist2D, bCount, binned, E);
        bucket_fill<<<nbBkt, 512, 0, stream>>>(binned, bCount, degi, cursor, mid, csr, N, Nhalf);
        embed_gemm1_q8<<<nbN, 256, 0, stream>>>(x, emb, W1, degi, P8, N);
        {
            const float* bb = b1;
            void* args[] = {(void*)&csr, (void*)&cursor, (void*)&mid, (void*)&degi,
                            (void*)&P8, (void*)&bb, (void*)&Qh, (void*)&stP1,
                            (void*)&N, (void*)&Nhalf};
            if (hipLaunchCooperativeKernel((const void*)gather_coop, dim3(GBLK),
                                           dim3(256), args, 0, stream) != hipSuccess)
                gather_stats_q8<<<nbG, 256, 0, stream>>>(csr, cursor, degi, P8, b1, Qh, stP1, N);
        }
        bn_gemm_q8<<<nbN, 256, 0, stream>>>(Qh, stP1, invN, g1, be1, W2, degi, P8, N);
        {
            const float* bb = b2;
            void* args[] = {(void*)&csr, (void*)&cursor, (void*)&mid, (void*)&degi,
                            (void*)&P8, (void*)&bb, (void*)&Qh, (void*)&stP2,
                            (void*)&N, (void*)&Nhalf};
            if (hipLaunchCooperativeKernel((const void*)gather_coop, dim3(GBLK),
                                           dim3(256), args, 0, stream) != hipSuccess)
                gather_stats_q8<<<nbG, 256, 0, stream>>>(csr, cursor, degi, P8, b2, Qh, stP2, N);
        }
        final_kernel_p<<<nbN, 256, 0, stream>>>(Qh, stP2, invN, g2, be2, Wm1, bm1, Wm2, bm2, out, N);
    } else {
        // fallback: fp32 atomic-scatter path
        int*   degi  = (int*)d_ws;                  // N
        float* P     = (float*)(degi + N);          // N*D
        float* Q     = P + (size_t)N * D;           // N*D
        float* stats = Q + (size_t)N * D;           // 100
        float* st1 = stats;
        float* st2 = stats + 50;

        hipMemsetAsync(degi, 0, (size_t)N * sizeof(int), stream);
        hipMemsetAsync(stats, 0, 100 * sizeof(float), stream);

        hist_kernel<<<nbE, 256, 0, stream>>>(dst, degi, E);
        embed_gemm1<<<nbN, 256, 0, stream>>>(x, emb, W1, degi, P, Q, N);
        scatter_kernel<<<nbS, 256, 0, stream>>>(src, dst, P, Q, E);
        transform_kernel<<<nbN, 256, 0, stream>>>(Q, degi, b1, N);
        stats_kernel<<<STATS_BLOCKS, 256, 0, stream>>>(Q, st1, N);
        bn_gemm<<<nbN, 256, 0, stream>>>(Q, st1, invN, g1, be1, W2, degi, P, Q, N);
        scatter_kernel<<<nbS, 256, 0, stream>>>(src, dst, P, Q, E);
        transform_kernel<<<nbN, 256, 0, stream>>>(Q, degi, b2, N);
        stats_kernel<<<STATS_BLOCKS, 256, 0, stream>>>(Q, st2, N);
        final_kernel<<<nbN, 256, 0, stream>>>(Q, st2, invN, g2, be2, Wm1, bm1, Wm2, bm2, out, N);
    }
}

// Round 10
// 269.459 us; speedup vs baseline: 6.8473x; 2.4170x over previous
//
#include <hip/hip_runtime.h>
#include <hip/hip_fp16.h>
#include <math.h>

#define D 25
#define STATS_BLOCKS 512
#define NBKT 512        // buckets of 512 nodes
#define BSH 9
#define BMSK 511
#define BIN_EDGES 8192  // edges per bin block
#define SORT_CAP 10240  // LDS sort capacity per bucket (avg ~8.2k)
#define NSLOT 64        // replicated stat partial slots
#define EPS 1e-5f

typedef unsigned int u32;
typedef unsigned long long u64;
typedef unsigned int u32x4 __attribute__((ext_vector_type(4)));  // native vector: OK for nontemporal builtins

// ---------------- binA: per-(block,bucket) histogram + stPart zeroing ----------------
__global__ __launch_bounds__(256) void binA(const int* __restrict__ dst,
                                            int* __restrict__ hist2D,
                                            float* __restrict__ stPart, int E) {
    if (blockIdx.x < 25) stPart[blockIdx.x * 256 + threadIdx.x] = 0.0f;
    __shared__ int h[NBKT];
    h[threadIdx.x] = 0;
    h[threadIdx.x + 256] = 0;
    __syncthreads();
    int base = blockIdx.x * BIN_EDGES;
#pragma unroll
    for (int j = 0; j < 32; ++j) {
        int idx = base + j * 256 + threadIdx.x;
        if (idx < E) atomicAdd(&h[dst[idx] >> BSH], 1);
    }
    __syncthreads();
    hist2D[blockIdx.x * NBKT + threadIdx.x] = h[threadIdx.x];
    hist2D[blockIdx.x * NBKT + threadIdx.x + 256] = h[threadIdx.x + 256];
}

// ------- colscan: per bucket, exclusive scan over blocks (in place) + total -------
__global__ __launch_bounds__(512) void colscan(int* __restrict__ hist2D,
                                               int* __restrict__ bCount, int nbBin) {
    __shared__ int s[512];
    int b = blockIdx.x;
    int j = threadIdx.x;
    int v = (j < nbBin) ? hist2D[j * NBKT + b] : 0;
    s[j] = v;
    __syncthreads();
    for (int off = 1; off < 512; off <<= 1) {
        int x = (j >= off) ? s[j - off] : 0;
        __syncthreads();
        s[j] += x;
        __syncthreads();
    }
    if (j < nbBin) hist2D[j * NBKT + b] = s[j] - v;   // exclusive prefix
    if (j == 0) bCount[b] = s[511];
}

// ------- binB (512 thr): inline scan of bCount for bases; write keys grouped by bucket -------
__global__ __launch_bounds__(512) void binB(const int* __restrict__ src,
                                            const int* __restrict__ dst,
                                            const int* __restrict__ hist2D,
                                            const int* __restrict__ bCount,
                                            int* __restrict__ binned, int E) {
    __shared__ int rank[NBKT], basew[NBKT], sc[NBKT];
    int t = threadIdx.x;
    int cnt = bCount[t];
    sc[t] = cnt;
    rank[t] = 0;
    __syncthreads();
    for (int off = 1; off < NBKT; off <<= 1) {
        int x = (t >= off) ? sc[t - off] : 0;
        __syncthreads();
        sc[t] += x;
        __syncthreads();
    }
    basew[t] = (sc[t] - cnt) + hist2D[blockIdx.x * NBKT + t];
    __syncthreads();
    int base = blockIdx.x * BIN_EDGES;
#pragma unroll
    for (int j = 0; j < 16; ++j) {
        int idx = base + j * 512 + t;
        if (idx < E) {
            int d = dst[idx];
            int b = d >> BSH;
            int r = atomicAdd(&rank[b], 1);
            binned[basew[b] + r] = (src[idx] << BSH) | (d & BMSK);
        }
    }
}

// ------- bucket_fill (512 thr): sort bucket b (512 nodes) in LDS, coalesced csr writeout -------
__global__ __launch_bounds__(512) void bucket_fill(
        const int* __restrict__ binned, const int* __restrict__ bCount,
        int* __restrict__ degi, int* __restrict__ cursor, int* __restrict__ csr, int N) {
    int b = blockIdx.x;
    int nodeBase = b << BSH;
    if (nodeBase >= N) return;
    __shared__ int h[NBKT];
    __shared__ int s2[512];
    __shared__ int sorted[SORT_CAP];
    int t = threadIdx.x;
    // parallel reduce of bCount[0..b-1] into base
    s2[t] = (t < b) ? bCount[t] : 0;
    __syncthreads();
    for (int off = 256; off > 0; off >>= 1) {
        if (t < off) s2[t] += s2[t + off];
        __syncthreads();
    }
    int s = s2[0];
    __syncthreads();
    h[t] = 0;
    __syncthreads();
    int cnt = bCount[b];
    int e = s + cnt;
    // degree histogram
    for (int k = s + t; k < e; k += 512)
        atomicAdd(&h[binned[k] & BMSK], 1);
    __syncthreads();
    int dg = h[t];
    int node = nodeBase + t;
    if (node < N) degi[node] = dg;
    s2[t] = dg;
    __syncthreads();
    for (int off = 1; off < 512; off <<= 1) {
        int x = (t >= off) ? s2[t - off] : 0;
        __syncthreads();
        s2[t] += x;
        __syncthreads();
    }
    int start = s2[t] - dg;            // local row start
    h[t] = start;                      // becomes cursor for fill
    if (node < N) cursor[node] = s + s2[t];   // global row end
    __syncthreads();
    if (cnt <= SORT_CAP) {
        // scatter into LDS, then coalesced writeout
        for (int k = s + t; k < e; k += 512) {
            int key = binned[k];
            int p = atomicAdd(&h[key & BMSK], 1);
            sorted[p] = key >> BSH;
        }
        __syncthreads();
        for (int j = t; j < cnt; j += 512)
            csr[s + j] = sorted[j];
    } else {
        // overflow fallback: direct global scatter
        for (int k = s + t; k < e; k += 512) {
            int key = binned[k];
            int p = atomicAdd(&h[key & BMSK], 1);
            csr[s + p] = key >> BSH;
        }
    }
}

// ================= int8-quantized row format =================
// row = 32 B: dwords 0..6 hold 25 int8 (bytes 25..27 zero), dword 7 = fp32 scale.
// value[d] = (int8)byte[d] * scale.  scale = rowmax/127, round-to-nearest.

__device__ __forceinline__ void quant_store_q8(u32* __restrict__ P8, int i,
                                               const float* v) {
    float mx = 0.0f;
#pragma unroll
    for (int d = 0; d < D; ++d) mx = fmaxf(mx, fabsf(v[d]));
    float scale = mx * (1.0f / 127.0f);
    float inv = (mx > 0.0f) ? (127.0f / mx) : 0.0f;
    u32 w[8];
#pragma unroll
    for (int dw = 0; dw < 7; ++dw) {
        u32 p = 0;
#pragma unroll
        for (int j = 0; j < 4; ++j) {
            int d = dw * 4 + j;
            int q = (d < D) ? __float2int_rn(v[d] * inv) : 0;
            p |= ((u32)q & 255u) << (8 * j);
        }
        w[dw] = p;
    }
    w[7] = __float_as_uint(scale);
    uint4* o = (uint4*)(P8 + ((size_t)i << 3));
    o[0] = make_uint4(w[0], w[1], w[2], w[3]);
    o[1] = make_uint4(w[4], w[5], w[6], w[7]);
}

// unpack 8 int8 (lo,hi dwords) and accumulate into 8 dims with scale c
__device__ __forceinline__ void acc8(u32 lo, u32 hi, float c,
        float& a0, float& a1, float& a2, float& a3,
        float& a4, float& a5, float& a6, float& a7) {
    a0 = fmaf(c, (float)((int)(lo << 24) >> 24), a0);
    a1 = fmaf(c, (float)((int)(lo << 16) >> 24), a1);
    a2 = fmaf(c, (float)((int)(lo <<  8) >> 24), a2);
    a3 = fmaf(c, (float)((int)lo >> 24), a3);
    a4 = fmaf(c, (float)((int)(hi << 24) >> 24), a4);
    a5 = fmaf(c, (float)((int)(hi << 16) >> 24), a5);
    a6 = fmaf(c, (float)((int)(hi <<  8) >> 24), a6);
    a7 = fmaf(c, (float)((int)hi >> 24), a7);
}

// ------------- layer1: P8 = q8(dinv * (emb[x] @ W1)) -------------
__global__ __launch_bounds__(256) void embed_gemm1_q8(
        const int* __restrict__ x, const float* __restrict__ emb,
        const float* __restrict__ W1, const int* __restrict__ degi,
        u32* __restrict__ P8, int N) {
    __shared__ float sW[D * D];
    for (int j = threadIdx.x; j < D * D; j += blockDim.x) sW[j] = W1[j];
    __syncthreads();
    int i = blockIdx.x * blockDim.x + threadIdx.x;
    if (i >= N) return;
    const float* er = emb + (size_t)x[i] * D;
    float t[D];
#pragma unroll
    for (int k = 0; k < D; ++k) t[k] = er[k];
    float dinv = rsqrtf((float)degi[i] + 1.0f);
    float v[D];
#pragma unroll
    for (int d = 0; d < D; ++d) {
        float acc = 0.0f;
#pragma unroll
        for (int k = 0; k < D; ++k) acc = fmaf(t[k], sW[k * D + d], acc);
        v[d] = dinv * acc;
    }
    quant_store_q8(P8, i, v);
}

// ------- gather + fused BN-stats, 4 lanes per node (uint2 row loads):
//   - per edge: 4 lane-addresses for the row (was 8) + 1 for csr (was 8):
//     lane f loads csr[k+f]/csr[k+4+f] once, indices distributed via __shfl(.,j,4)
//   - 8 edges in flight; 4-edge mid-block shrinks the serial tail
//   - lane f owns dims [8f, 8f+8); lane 3: dim 24 + row scale in w.y -------
__global__ __launch_bounds__(256) void gather_stats_q8(
        const int* __restrict__ csr, const int* __restrict__ cursor,
        const int* __restrict__ degi, const uint2* __restrict__ P8v,
        const float* __restrict__ bias, __half* __restrict__ Qh,
        float* __restrict__ stPart, int N) {
    __shared__ float red[4][4][16];
    int t = threadIdx.x;
    int node = blockIdx.x * 64 + (t >> 2);
    int f = t & 3;                  // uint2 index within the 32 B row
    float a0 = 0.f, a1 = 0.f, a2 = 0.f, a3 = 0.f;
    float a4 = 0.f, a5 = 0.f, a6 = 0.f, a7 = 0.f;
    float q0 = 0.f, q1 = 0.f, q2 = 0.f, q3 = 0.f;
    float q4 = 0.f, q5 = 0.f, q6 = 0.f, q7 = 0.f;
    if (node < N) {
        int end = cursor[node];
        int dg  = degi[node];
        int k = end - dg;
        // self loop
        {
            uint2 w = P8v[((size_t)node << 2) + f];
            float c = __shfl(__uint_as_float(w.y), 3, 4);
            u32 hi = (f == 3) ? 0u : w.y;
            acc8(w.x, hi, c, a0, a1, a2, a3, a4, a5, a6, a7);
        }
        for (; k + 8 <= end; k += 8) {
            int eL = __builtin_nontemporal_load(csr + k + f);
            int eH = __builtin_nontemporal_load(csr + k + 4 + f);
            int e0 = __shfl(eL, 0, 4), e1 = __shfl(eL, 1, 4),
                e2 = __shfl(eL, 2, 4), e3 = __shfl(eL, 3, 4);
            int e4 = __shfl(eH, 0, 4), e5 = __shfl(eH, 1, 4),
                e6 = __shfl(eH, 2, 4), e7 = __shfl(eH, 3, 4);
            uint2 w0 = P8v[((size_t)e0 << 2) + f];
            uint2 w1 = P8v[((size_t)e1 << 2) + f];
            uint2 w2 = P8v[((size_t)e2 << 2) + f];
            uint2 w3 = P8v[((size_t)e3 << 2) + f];
            uint2 w4 = P8v[((size_t)e4 << 2) + f];
            uint2 w5 = P8v[((size_t)e5 << 2) + f];
            uint2 w6 = P8v[((size_t)e6 << 2) + f];
            uint2 w7 = P8v[((size_t)e7 << 2) + f];
            float c0 = __shfl(__uint_as_float(w0.y), 3, 4);
            float c1 = __shfl(__uint_as_float(w1.y), 3, 4);
            float c2 = __shfl(__uint_as_float(w2.y), 3, 4);
            float c3 = __shfl(__uint_as_float(w3.y), 3, 4);
            float c4 = __shfl(__uint_as_float(w4.y), 3, 4);
            float c5 = __shfl(__uint_as_float(w5.y), 3, 4);
            float c6 = __shfl(__uint_as_float(w6.y), 3, 4);
            float c7 = __shfl(__uint_as_float(w7.y), 3, 4);
            bool m = (f == 3);
            acc8(w0.x, m ? 0u : w0.y, c0, a0, a1, a2, a3, a4, a5, a6, a7);
            acc8(w1.x, m ? 0u : w1.y, c1, a0, a1, a2, a3, a4, a5, a6, a7);
            acc8(w2.x, m ? 0u : w2.y, c2, a0, a1, a2, a3, a4, a5, a6, a7);
            acc8(w3.x, m ? 0u : w3.y, c3, a0, a1, a2, a3, a4, a5, a6, a7);
            acc8(w4.x, m ? 0u : w4.y, c4, a0, a1, a2, a3, a4, a5, a6, a7);
            acc8(w5.x, m ? 0u : w5.y, c5, a0, a1, a2, a3, a4, a5, a6, a7);
            acc8(w6.x, m ? 0u : w6.y, c6, a0, a1, a2, a3, a4, a5, a6, a7);
            acc8(w7.x, m ? 0u : w7.y, c7, a0, a1, a2, a3, a4, a5, a6, a7);
        }
        if (k + 4 <= end) {
            int eL = __builtin_nontemporal_load(csr + k + f);
            int e0 = __shfl(eL, 0, 4), e1 = __shfl(eL, 1, 4),
                e2 = __shfl(eL, 2, 4), e3 = __shfl(eL, 3, 4);
            uint2 w0 = P8v[((size_t)e0 << 2) + f];
            uint2 w1 = P8v[((size_t)e1 << 2) + f];
            uint2 w2 = P8v[((size_t)e2 << 2) + f];
            uint2 w3 = P8v[((size_t)e3 << 2) + f];
            float c0 = __shfl(__uint_as_float(w0.y), 3, 4);
            float c1 = __shfl(__uint_as_float(w1.y), 3, 4);
            float c2 = __shfl(__uint_as_float(w2.y), 3, 4);
            float c3 = __shfl(__uint_as_float(w3.y), 3, 4);
            bool m = (f == 3);
            acc8(w0.x, m ? 0u : w0.y, c0, a0, a1, a2, a3, a4, a5, a6, a7);
            acc8(w1.x, m ? 0u : w1.y, c1, a0, a1, a2, a3, a4, a5, a6, a7);
            acc8(w2.x, m ? 0u : w2.y, c2, a0, a1, a2, a3, a4, a5, a6, a7);
            acc8(w3.x, m ? 0u : w3.y, c3, a0, a1, a2, a3, a4, a5, a6, a7);
            k += 4;
        }
        for (; k < end; ++k) {
            int e = __builtin_nontemporal_load(csr + k);
            uint2 w = P8v[((size_t)e << 2) + f];
            float c = __shfl(__uint_as_float(w.y), 3, 4);
            u32 hi = (f == 3) ? 0u : w.y;
            acc8(w.x, hi, c, a0, a1, a2, a3, a4, a5, a6, a7);
        }
        float dinv = rsqrtf((float)dg + 1.0f);
        int j0 = f << 3;
        if (f < 3) {
            q0 = fmaf(dinv, a0, bias[j0]);
            q1 = fmaf(dinv, a1, bias[j0 + 1]);
            q2 = fmaf(dinv, a2, bias[j0 + 2]);
            q3 = fmaf(dinv, a3, bias[j0 + 3]);
            q4 = fmaf(dinv, a4, bias[j0 + 4]);
            q5 = fmaf(dinv, a5, bias[j0 + 5]);
            q6 = fmaf(dinv, a6, bias[j0 + 6]);
            q7 = fmaf(dinv, a7, bias[j0 + 7]);
        } else {
            q0 = fmaf(dinv, a0, bias[24]);   // dim 24; q1..q7 stay 0 (pad)
        }
        __half2 h01 = __floats2half2_rn(q0, q1);
        __half2 h23 = __floats2half2_rn(q2, q3);
        __half2 h45 = __floats2half2_rn(q4, q5);
        __half2 h67 = __floats2half2_rn(q6, q7);
        u32x4 cv;
        cv.x = *(u32*)&h01;
        cv.y = *(u32*)&h23;
        cv.z = *(u32*)&h45;
        cv.w = *(u32*)&h67;
        __builtin_nontemporal_store(cv, (u32x4*)Qh + ((size_t)node << 2) + f);
    }
    // ---- fused BN stats: lane f owns dims 8f..8f+7 (sum + sumsq = 16 values) ----
    float r[16] = {q0, q1, q2, q3, q4, q5, q6, q7,
                   q0 * q0, q1 * q1, q2 * q2, q3 * q3,
                   q4 * q4, q5 * q5, q6 * q6, q7 * q7};
#pragma unroll
    for (int v = 0; v < 16; ++v) {
        r[v] += __shfl_down(r[v], 32, 64);
        r[v] += __shfl_down(r[v], 16, 64);
        r[v] += __shfl_down(r[v], 8, 64);
        r[v] += __shfl_down(r[v], 4, 64);
    }
    int wv = t >> 6;
    if ((t & 63) < 4) {
#pragma unroll
        for (int v = 0; v < 16; ++v) red[wv][f][v] = r[v];
    }
    __syncthreads();
    if (t < 64) {
        int f2 = t >> 4, i = t & 15;
        float tot = red[0][f2][i] + red[1][f2][i] + red[2][f2][i] + red[3][f2][i];
        int a = (f2 << 3) + (i & 7);
        if (a < D)
            atomicAdd(&stPart[(blockIdx.x & (NSLOT - 1)) * 50 + (i >> 3) * D + a], tot);
    }
}

// ------- layer2: reduce stPart -> mu/rstd; t = relu(bn(Qh)); P8 = q8(dinv*(t@W2)) -------
__global__ __launch_bounds__(256) void bn_gemm_q8(
        const __half* __restrict__ Qh, const float* __restrict__ stPart, float invN,
        const float* __restrict__ g, const float* __restrict__ be,
        const float* __restrict__ W, const int* __restrict__ degi,
        u32* __restrict__ P8, int N) {
    __shared__ float sW[D * D];
    __shared__ float sScale[D], sShift[D];
    __shared__ float sSum[2 * D];
    for (int j = threadIdx.x; j < D * D; j += blockDim.x) sW[j] = W[j];
    if (threadIdx.x < 2 * D) {
        float a = 0.0f;
        for (int k = 0; k < NSLOT; ++k) a += stPart[k * 50 + threadIdx.x];
        sSum[threadIdx.x] = a;
    }
    __syncthreads();
    if (threadIdx.x < D) {
        float m = sSum[threadIdx.x] * invN;
        float v = fmaxf(sSum[D + threadIdx.x] * invN - m * m, 0.0f);
        float sc = rsqrtf(v + EPS) * g[threadIdx.x];
        sScale[threadIdx.x] = sc;
        sShift[threadIdx.x] = be[threadIdx.x] - m * sc;
    }
    __syncthreads();
    int i = blockIdx.x * blockDim.x + threadIdx.x;
    if (i >= N) return;
    const __half2* qrow = (const __half2*)Qh + ((size_t)i << 4);
    float t[D];
#pragma unroll
    for (int ff = 0; ff < 13; ++ff) {
        float2 v = __half22float2(qrow[ff]);
        int j0 = ff << 1;
        t[j0] = fmaxf(0.0f, fmaf(v.x, sScale[j0], sShift[j0]));
        if (ff < 12) t[j0 + 1] = fmaxf(0.0f, fmaf(v.y, sScale[j0 + 1], sShift[j0 + 1]));
    }
    float dinv = rsqrtf((float)degi[i] + 1.0f);
    float vout[D];
#pragma unroll
    for (int d = 0; d < D; ++d) {
        float acc = 0.0f;
#pragma unroll
        for (int k = 0; k < D; ++k) acc = fmaf(t[k], sW[k * D + d], acc);
        vout[d] = dinv * acc;
    }
    quant_store_q8(P8, i, vout);
}

// ------- head: reduce stPart -> mu/rstd; t = relu(bn(Qh)); MLP; sigmoid -------
__global__ __launch_bounds__(256) void final_kernel_p(
        const __half* __restrict__ Qh, const float* __restrict__ stPart, float invN,
        const float* __restrict__ g, const float* __restrict__ be,
        const float* __restrict__ Wm1, const float* __restrict__ bm1,
        const float* __restrict__ Wm2, const float* __restrict__ bm2,
        float* __restrict__ out, int N) {
    __shared__ float sW1[D * 12];
    __shared__ float sb1[12], sW2[12];
    __shared__ float sScale[D], sShift[D];
    __shared__ float sSum[2 * D];
    __shared__ float sb2;
    for (int j = threadIdx.x; j < D * 12; j += blockDim.x) sW1[j] = Wm1[j];
    if (threadIdx.x < 12) {
        sb1[threadIdx.x] = bm1[threadIdx.x];
        sW2[threadIdx.x] = Wm2[threadIdx.x];
    }
    if (threadIdx.x < 2 * D) {
        float a = 0.0f;
        for (int k = 0; k < NSLOT; ++k) a += stPart[k * 50 + threadIdx.x];
        sSum[threadIdx.x] = a;
    }
    if (threadIdx.x == 0) sb2 = bm2[0];
    __syncthreads();
    if (threadIdx.x < D) {
        float m = sSum[threadIdx.x] * invN;
        float v = fmaxf(sSum[D + threadIdx.x] * invN - m * m, 0.0f);
        float sc = rsqrtf(v + EPS) * g[threadIdx.x];
        sScale[threadIdx.x] = sc;
        sShift[threadIdx.x] = be[threadIdx.x] - m * sc;
    }
    __syncthreads();
    int i = blockIdx.x * blockDim.x + threadIdx.x;
    if (i >= N) return;
    const __half2* qrow = (const __half2*)Qh + ((size_t)i << 4);
    float t[D];
#pragma unroll
    for (int ff = 0; ff < 13; ++ff) {
        float2 v = __half22float2(qrow[ff]);
        int j0 = ff << 1;
        t[j0] = fmaxf(0.0f, fmaf(v.x, sScale[j0], sShift[j0]));
        if (ff < 12) t[j0 + 1] = fmaxf(0.0f, fmaf(v.y, sScale[j0 + 1], sShift[j0 + 1]));
    }
    float z = sb2;
#pragma unroll
    for (int j = 0; j < 12; ++j) {
        float m = sb1[j];
#pragma unroll
        for (int k = 0; k < D; ++k) m = fmaf(t[k], sW1[k * 12 + j], m);
        m = fmaxf(0.0f, m);
        z = fmaf(m, sW2[j], z);
    }
    out[i] = 1.0f / (1.0f + expf(-z));
}

// ================= fallback kernels (atomic-scatter path, fp32) =================
__global__ void hist_kernel(const int* __restrict__ dst, int* __restrict__ degi, int E) {
    int e = blockIdx.x * blockDim.x + threadIdx.x;
    if (e < E) atomicAdd(&degi[dst[e]], 1);
}

__global__ __launch_bounds__(256) void embed_gemm1(
        const int* __restrict__ x, const float* __restrict__ emb,
        const float* __restrict__ W1, const int* __restrict__ degi,
        float* __restrict__ P, float* __restrict__ Qdup, int N) {
    __shared__ float sW[D * D];
    for (int j = threadIdx.x; j < D * D; j += blockDim.x) sW[j] = W1[j];
    __syncthreads();
    int i = blockIdx.x * blockDim.x + threadIdx.x;
    if (i >= N) return;
    const float* er = emb + (size_t)x[i] * D;
    float t[D];
#pragma unroll
    for (int k = 0; k < D; ++k) t[k] = er[k];
    float dinv = rsqrtf((float)degi[i] + 1.0f);
#pragma unroll
    for (int d = 0; d < D; ++d) {
        float acc = 0.0f;
#pragma unroll
        for (int k = 0; k < D; ++k) acc = fmaf(t[k], sW[k * D + d], acc);
        float v = dinv * acc;
        P[i * D + d] = v;
        if (Qdup) Qdup[i * D + d] = v;
    }
}

__global__ void scatter_kernel(const int* __restrict__ src, const int* __restrict__ dst,
                               const float* __restrict__ A, float* __restrict__ B, int E) {
    int idx = blockIdx.x * blockDim.x + threadIdx.x;
    int e = idx >> 5;
    int lane = idx & 31;
    if (e >= E || lane >= D) return;
    atomicAdd(&B[dst[e] * D + lane], A[src[e] * D + lane]);
}

__global__ __launch_bounds__(256) void transform_kernel(
        float* __restrict__ Q, const int* __restrict__ degi,
        const float* __restrict__ bias, int N) {
    int i = blockIdx.x * blockDim.x + threadIdx.x;
    if (i >= N) return;
    float dinv = rsqrtf((float)degi[i] + 1.0f);
#pragma unroll
    for (int d = 0; d < D; ++d)
        Q[i * D + d] = fmaf(dinv, Q[i * D + d], bias[d]);
}

__global__ __launch_bounds__(256) void stats_kernel(
        const float* __restrict__ Q, float* __restrict__ st, int N) {
    float ls[D], lq[D];
#pragma unroll
    for (int d = 0; d < D; ++d) { ls[d] = 0.0f; lq[d] = 0.0f; }
    for (int i = blockIdx.x * blockDim.x + threadIdx.x; i < N;
         i += gridDim.x * blockDim.x) {
#pragma unroll
        for (int d = 0; d < D; ++d) {
            float v = Q[i * D + d];
            ls[d] += v;
            lq[d] += v * v;
        }
    }
#pragma unroll
    for (int d = 0; d < D; ++d) {
        for (int off = 32; off > 0; off >>= 1) {
            ls[d] += __shfl_down(ls[d], off, 64);
            lq[d] += __shfl_down(lq[d], off, 64);
        }
    }
    __shared__ float red[4][2 * D];
    int wave = threadIdx.x >> 6;
    int lane = threadIdx.x & 63;
    if (lane == 0) {
#pragma unroll
        for (int d = 0; d < D; ++d) {
            red[wave][d] = ls[d];
            red[wave][D + d] = lq[d];
        }
    }
    __syncthreads();
    if (threadIdx.x < 2 * D) {
        float t = red[0][threadIdx.x] + red[1][threadIdx.x] +
                  red[2][threadIdx.x] + red[3][threadIdx.x];
        atomicAdd(&st[threadIdx.x], t);
    }
}

__global__ __launch_bounds__(256) void bn_gemm(
        const float* __restrict__ Qin, const float* __restrict__ st, float invN,
        const float* __restrict__ g, const float* __restrict__ be,
        const float* __restrict__ W, const int* __restrict__ degi,
        float* __restrict__ P, float* __restrict__ Qdup, int N) {
    __shared__ float sW[D * D];
    __shared__ float sScale[D], sShift[D];
    for (int j = threadIdx.x; j < D * D; j += blockDim.x) sW[j] = W[j];
    if (threadIdx.x < D) {
        float m = st[threadIdx.x] * invN;
        float v = fmaxf(st[D + threadIdx.x] * invN - m * m, 0.0f);
        float sc = rsqrtf(v + EPS) * g[threadIdx.x];
        sScale[threadIdx.x] = sc;
        sShift[threadIdx.x] = be[threadIdx.x] - m * sc;
    }
    __syncthreads();
    int i = blockIdx.x * blockDim.x + threadIdx.x;
    if (i >= N) return;
    float t[D];
#pragma unroll
    for (int d = 0; d < D; ++d)
        t[d] = fmaxf(0.0f, fmaf(Qin[i * D + d], sScale[d], sShift[d]));
    float dinv = rsqrtf((float)degi[i] + 1.0f);
#pragma unroll
    for (int d = 0; d < D; ++d) {
        float acc = 0.0f;
#pragma unroll
        for (int k = 0; k < D; ++k) acc = fmaf(t[k], sW[k * D + d], acc);
        float v = dinv * acc;
        P[i * D + d] = v;
        if (Qdup) Qdup[i * D + d] = v;
    }
}

__global__ __launch_bounds__(256) void final_kernel(
        const float* __restrict__ Q, const float* __restrict__ st, float invN,
        const float* __restrict__ g, const float* __restrict__ be,
        const float* __restrict__ Wm1, const float* __restrict__ bm1,
        const float* __restrict__ Wm2, const float* __restrict__ bm2,
        float* __restrict__ out, int N) {
    __shared__ float sW1[D * 12];
    __shared__ float sb1[12], sW2[12];
    __shared__ float sScale[D], sShift[D];
    __shared__ float sb2;
    for (int j = threadIdx.x; j < D * 12; j += blockDim.x) sW1[j] = Wm1[j];
    if (threadIdx.x < 12) {
        sb1[threadIdx.x] = bm1[threadIdx.x];
        sW2[threadIdx.x] = Wm2[threadIdx.x];
    }
    if (threadIdx.x < D) {
        float m = st[threadIdx.x] * invN;
        float v = fmaxf(st[D + threadIdx.x] * invN - m * m, 0.0f);
        float sc = rsqrtf(v + EPS) * g[threadIdx.x];
        sScale[threadIdx.x] = sc;
        sShift[threadIdx.x] = be[threadIdx.x] - m * sc;
    }
    if (threadIdx.x == 0) sb2 = bm2[0];
    __syncthreads();
    int i = blockIdx.x * blockDim.x + threadIdx.x;
    if (i >= N) return;
    float t[D];
#pragma unroll
    for (int d = 0; d < D; ++d)
        t[d] = fmaxf(0.0f, fmaf(Q[i * D + d], sScale[d], sShift[d]));
    float z = sb2;
#pragma unroll
    for (int j = 0; j < 12; ++j) {
        float m = sb1[j];
#pragma unroll
        for (int k = 0; k < D; ++k) m = fmaf(t[k], sW1[k * 12 + j], m);
        m = fmaxf(0.0f, m);
        z = fmaf(m, sW2[j], z);
    }
    out[i] = 1.0f / (1.0f + expf(-z));
}

extern "C" void kernel_launch(void* const* d_in, const int* in_sizes, int n_in,
                              void* d_out, int out_size, void* d_ws, size_t ws_size,
                              hipStream_t stream) {
    const int*   x    = (const int*)d_in[0];
    const int*   ei   = (const int*)d_in[1];
    const float* emb  = (const float*)d_in[2];
    const float* W1   = (const float*)d_in[3];
    const float* b1   = (const float*)d_in[4];
    const float* g1   = (const float*)d_in[5];
    const float* be1  = (const float*)d_in[6];
    const float* W2   = (const float*)d_in[7];
    const float* b2   = (const float*)d_in[8];
    const float* g2   = (const float*)d_in[9];
    const float* be2  = (const float*)d_in[10];
    const float* Wm1  = (const float*)d_in[11];
    const float* bm1  = (const float*)d_in[12];
    const float* Wm2  = (const float*)d_in[13];
    const float* bm2  = (const float*)d_in[14];
    float* out = (float*)d_out;

    int N = in_sizes[0];
    int E = in_sizes[1] / 2;
    const int* src = ei;
    const int* dst = ei + E;
    float invN = 1.0f / (float)N;

    int nbBin = (E + BIN_EDGES - 1) / BIN_EDGES;
    // words: degi N + cursor N + csr E + bCount 512 + hist2D nbBin*512
    //        + P8 8N + Qh 16N + stPart 6400 + align slack
    size_t csrNeed = ((size_t)26 * N + E + 512 + (size_t)nbBin * NBKT +
                      2 * NSLOT * 50 + 16) * 4;
    bool useCSR = (ws_size >= csrNeed) && (N <= NBKT * 512) && (nbBin <= 512) &&
                  ((size_t)E <= (size_t)16 * N) && (nbBin >= 25);

    int nbN  = (N + 255) / 256;
    int nbE  = (E + 255) / 256;
    int nbG  = (N + 63) / 64;            // 64 nodes per 256-thread block (4 lanes/node)
    int nbS  = (int)(((long)E * 32 + 255) / 256);

    if (useCSR) {
        int*    degi    = (int*)d_ws;                   // N
        int*    cursor  = degi + N;                     // N
        int*    csr     = cursor + N;                   // E
        int*    bCount  = csr + E;                      // 512
        int*    hist2D  = bCount + NBKT;                // nbBin*512
        int*    hEnd    = hist2D + (size_t)nbBin * NBKT;
        u32*    P8      = (u32*)(((uintptr_t)hEnd + 15) & ~(uintptr_t)15); // 8N dwords (N rows x 32 B)
        __half* Qh      = (__half*)(P8 + 8 * (size_t)N);                   // 32N halves = 16N dwords
        float*  stP1    = (float*)((u32*)Qh + 16 * (size_t)N);             // 64*50
        float*  stP2    = stP1 + NSLOT * 50;                               // 64*50
        int*    binned  = (int*)Qh;   // E ints (aliases Qh; dead before Qh written; E<=16N)

        int nbBkt = (N + 511) / 512;

        binA<<<nbBin, 256, 0, stream>>>(dst, hist2D, stP1, E);
        colscan<<<NBKT, 512, 0, stream>>>(hist2D, bCount, nbBin);
        binB<<<nbBin, 512, 0, stream>>>(src, dst, hist2D, bCount, binned, E);
        bucket_fill<<<nbBkt, 512, 0, stream>>>(binned, bCount, degi, cursor, csr, N);
        embed_gemm1_q8<<<nbN, 256, 0, stream>>>(x, emb, W1, degi, P8, N);
        gather_stats_q8<<<nbG, 256, 0, stream>>>(csr, cursor, degi, (const uint2*)P8, b1, Qh, stP1, N);
        bn_gemm_q8<<<nbN, 256, 0, stream>>>(Qh, stP1, invN, g1, be1, W2, degi, P8, N);
        gather_stats_q8<<<nbG, 256, 0, stream>>>(csr, cursor, degi, (const uint2*)P8, b2, Qh, stP2, N);
        final_kernel_p<<<nbN, 256, 0, stream>>>(Qh, stP2, invN, g2, be2, Wm1, bm1, Wm2, bm2, out, N);
    } else {
        // fallback: fp32 atomic-scatter path
        int*   degi  = (int*)d_ws;                  // N
        float* P     = (float*)(degi + N);          // N*D
        float* Q     = P + (size_t)N * D;           // N*D
        float* stats = Q + (size_t)N * D;           // 100
        float* st1 = stats;
        float* st2 = stats + 50;

        (void)hipMemsetAsync(degi, 0, (size_t)N * sizeof(int), stream);
        (void)hipMemsetAsync(stats, 0, 100 * sizeof(float), stream);

        hist_kernel<<<nbE, 256, 0, stream>>>(dst, degi, E);
        embed_gemm1<<<nbN, 256, 0, stream>>>(x, emb, W1, degi, P, Q, N);
        scatter_kernel<<<nbS, 256, 0, stream>>>(src, dst, P, Q, E);
        transform_kernel<<<nbN, 256, 0, stream>>>(Q, degi, b1, N);
        stats_kernel<<<STATS_BLOCKS, 256, 0, stream>>>(Q, st1, N);
        bn_gemm<<<nbN, 256, 0, stream>>>(Q, st1, invN, g1, be1, W2, degi, P, Q, N);
        scatter_kernel<<<nbS, 256, 0, stream>>>(src, dst, P, Q, E);
        transform_kernel<<<nbN, 256, 0, stream>>>(Q, degi, b2, N);
        stats_kernel<<<STATS_BLOCKS, 256, 0, stream>>>(Q, st2, N);
        final_kernel<<<nbN, 256, 0, stream>>>(Q, st2, invN, g2, be2, Wm1, bm1, Wm2, bm2, out, N);
    }
}